// Round 1
// baseline (1348.910 us; speedup 1.0000x reference)
//
#include <hip/hip_runtime.h>
#include <math.h>

#define DEVINL __device__ __forceinline__

constexpr int S_   = 1024;
constexpr int H_   = 512;
constexpr int NH_  = 8;
constexpr int L_   = 4;
constexpr int HD_  = 64;
constexpr int MLP_ = 2048;
constexpr int OUT_ = 128;
constexpr int B_   = 2;
constexpr int BS_  = 2048;   // B*S
constexpr int KTOP_ = 204;

typedef __bf16 bf16x8 __attribute__((ext_vector_type(8)));
typedef unsigned short u16x8 __attribute__((ext_vector_type(8)));
typedef float f32x4 __attribute__((ext_vector_type(4)));

DEVINL unsigned short f2b(float f) {
  unsigned int u = __float_as_uint(f);
  unsigned int r = (u + 0x7fffu + ((u >> 16) & 1u)) >> 16;  // RNE
  return (unsigned short)r;
}

// ---------------------------------------------------------------------------
// Transpose + f32->bf16 convert: src f32 [z][R][C] -> dst bf16 [z][C][R]
// ---------------------------------------------------------------------------
__global__ __launch_bounds__(256) void transpose_conv_kernel(
    const float* __restrict__ src, unsigned short* __restrict__ dst, int R, int C)
{
  __shared__ float tile[32][33];
  const size_t base = (size_t)blockIdx.z * R * C;
  src += base; dst += base;
  const int c0 = blockIdx.x * 32;
  const int r0 = blockIdx.y * 32;
  const int tx = threadIdx.x & 31;
  const int ty = threadIdx.x >> 5;   // 0..7
#pragma unroll
  for (int j = 0; j < 4; j++)
    tile[ty + j * 8][tx] = src[(size_t)(r0 + ty + j * 8) * C + c0 + tx];
  __syncthreads();
#pragma unroll
  for (int j = 0; j < 4; j++)
    dst[(size_t)(c0 + ty + j * 8) * R + r0 + tx] = f2b(tile[tx][ty + j * 8]);
}

// ---------------------------------------------------------------------------
// h[b,s,:] = x[b,s]*in_w + in_b + pos_encoding(s,:)
// ---------------------------------------------------------------------------
__global__ __launch_bounds__(128) void input_pe_kernel(
    const float* __restrict__ x, const float* __restrict__ in_w,
    const float* __restrict__ in_b, float* __restrict__ h)
{
  const int row = blockIdx.x;          // 0..2047
  const int s = row & (S_ - 1);
  const int c = threadIdx.x * 4;
  const float xv = x[row];
  const float4 wv = *(const float4*)(in_w + c);
  const float4 bv = *(const float4*)(in_b + c);
  const float* wp = (const float*)&wv;
  const float* bp = (const float*)&bv;
  float o[4];
#pragma unroll
  for (int j = 0; j < 4; j++) {
    const int cc = c + j;
    const float di = expf(-(float)(cc & ~1) * (9.210340371976184f / 512.0f));
    const float ang = (float)s * di;
    const float pe = (cc & 1) ? cosf(ang) : sinf(ang);
    o[j] = xv * wp[j] + bp[j] + pe;
  }
  *(float4*)(h + (size_t)row * H_ + c) = make_float4(o[0], o[1], o[2], o[3]);
}

// ---------------------------------------------------------------------------
// LayerNorm: f32 in -> bf16 out (row = 512)
// ---------------------------------------------------------------------------
__global__ __launch_bounds__(128) void ln_kernel(
    const float* __restrict__ hin, const float* __restrict__ g,
    const float* __restrict__ b, unsigned short* __restrict__ nout)
{
  const int row = blockIdx.x;
  const int t = threadIdx.x;
  const int wid = t >> 6, ln_ = t & 63;
  __shared__ float red[2];
  float4 v = ((const float4*)(hin + (size_t)row * H_))[t];
  float sm = v.x + v.y + v.z + v.w;
#pragma unroll
  for (int m = 1; m < 64; m <<= 1) sm += __shfl_xor(sm, m);
  if (ln_ == 0) red[wid] = sm;
  __syncthreads();
  const float mean = (red[0] + red[1]) * (1.0f / 512.0f);
  __syncthreads();
  const float dx = v.x - mean, dy = v.y - mean, dz = v.z - mean, dw = v.w - mean;
  float ss = dx * dx + dy * dy + dz * dz + dw * dw;
#pragma unroll
  for (int m = 1; m < 64; m <<= 1) ss += __shfl_xor(ss, m);
  if (ln_ == 0) red[wid] = ss;
  __syncthreads();
  const float var = (red[0] + red[1]) * (1.0f / 512.0f);
  const float rs = rsqrtf(var + 1e-5f);
  const float4 gv = ((const float4*)g)[t];
  const float4 bv = ((const float4*)b)[t];
  ushort4 o;
  o.x = f2b(dx * rs * gv.x + bv.x);
  o.y = f2b(dy * rs * gv.y + bv.y);
  o.z = f2b(dz * rs * gv.z + bv.z);
  o.w = f2b(dw * rs * gv.w + bv.w);
  ((ushort4*)(nout + (size_t)row * H_))[t] = o;
}

// ---------------------------------------------------------------------------
// GEMM: C[M,N] = epi(A[M,K](bf16) @ Bt[N,K]^T(bf16) + bias[N])
// EPI: 0 = bf16 out, 1 = f32 out += (residual in-place), 2 = gelu -> bf16,
//      3 = f32 out, 4 = bf16 transposed V store -> vt[B][512][S]
// 128x128 tile, BK=32, 4 waves (2x2 of 64x64), mfma_f32_16x16x32_bf16
// ---------------------------------------------------------------------------
template <int EPI>
__global__ __launch_bounds__(256, 2) void gemm_kernel(
    const unsigned short* __restrict__ A, const unsigned short* __restrict__ Bt,
    const float* __restrict__ bias, void* __restrict__ Cout, int M, int N, int K)
{
  constexpr int LDK = 56;   // padded LDS stride (112B: 16B-aligned, non-pow2 banks)
  __shared__ unsigned short Alds[128 * LDK];
  __shared__ unsigned short Blds[128 * LDK];
  const int tid = threadIdx.x;
  const int w = tid >> 6, lane = tid & 63, lr = lane & 15, lg = lane >> 4;
  const int m0 = blockIdx.x * 128, n0 = blockIdx.y * 128;
  const int wm = (w >> 1) * 64, wn = (w & 1) * 64;

  const int e0 = tid * 8;
  const int r0 = e0 >> 5, c0 = e0 & 31;
  const unsigned short* Ap0 = A + (size_t)(m0 + r0) * K + c0;
  const unsigned short* Ap1 = Ap0 + (size_t)64 * K;
  const unsigned short* Bp0 = Bt + (size_t)(n0 + r0) * K + c0;
  const unsigned short* Bp1 = Bp0 + (size_t)64 * K;
  unsigned short* AL0 = Alds + r0 * LDK + c0;
  unsigned short* AL1 = AL0 + 64 * LDK;
  unsigned short* BL0 = Blds + r0 * LDK + c0;
  unsigned short* BL1 = BL0 + 64 * LDK;

  const f32x4 zero4 = {0.f, 0.f, 0.f, 0.f};
  f32x4 acc[4][4];
#pragma unroll
  for (int i = 0; i < 4; i++)
#pragma unroll
    for (int j = 0; j < 4; j++) acc[i][j] = zero4;

  for (int kt = 0; kt < K; kt += 32) {
    const int4 a0 = *(const int4*)(Ap0 + kt);
    const int4 a1 = *(const int4*)(Ap1 + kt);
    const int4 b0 = *(const int4*)(Bp0 + kt);
    const int4 b1 = *(const int4*)(Bp1 + kt);
    __syncthreads();
    *(int4*)AL0 = a0; *(int4*)AL1 = a1;
    *(int4*)BL0 = b0; *(int4*)BL1 = b1;
    __syncthreads();
    bf16x8 af[4], bfr[4];
#pragma unroll
    for (int mi = 0; mi < 4; mi++)
      af[mi] = *(const bf16x8*)(Alds + (wm + mi * 16 + lr) * LDK + lg * 8);
#pragma unroll
    for (int ni = 0; ni < 4; ni++)
      bfr[ni] = *(const bf16x8*)(Blds + (wn + ni * 16 + lr) * LDK + lg * 8);
#pragma unroll
    for (int mi = 0; mi < 4; mi++)
#pragma unroll
      for (int ni = 0; ni < 4; ni++)
        acc[mi][ni] = __builtin_amdgcn_mfma_f32_16x16x32_bf16(af[mi], bfr[ni], acc[mi][ni], 0, 0, 0);
  }

#pragma unroll
  for (int mi = 0; mi < 4; mi++) {
#pragma unroll
    for (int ni = 0; ni < 4; ni++) {
      const int col = n0 + wn + ni * 16 + lr;
      const float bs = bias[col];
      if constexpr (EPI == 4) {
        const int row0 = m0 + wm + mi * 16 + lg * 4;
        const int bb = row0 >> 10, ssi = row0 & 1023;
        ushort4 pk;
        pk.x = f2b(acc[mi][ni][0] + bs);
        pk.y = f2b(acc[mi][ni][1] + bs);
        pk.z = f2b(acc[mi][ni][2] + bs);
        pk.w = f2b(acc[mi][ni][3] + bs);
        *(ushort4*)((unsigned short*)Cout + ((size_t)(bb * 512 + col)) * 1024 + ssi) = pk;
      } else {
#pragma unroll
        for (int r = 0; r < 4; r++) {
          const int row = m0 + wm + mi * 16 + lg * 4 + r;
          float val = acc[mi][ni][r] + bs;
          const size_t idx = (size_t)row * N + col;
          if constexpr (EPI == 0) {
            ((unsigned short*)Cout)[idx] = f2b(val);
          } else if constexpr (EPI == 1) {
            ((float*)Cout)[idx] += val;
          } else if constexpr (EPI == 2) {
            val = 0.5f * val * (1.0f + erff(val * 0.7071067811865475f));
            ((unsigned short*)Cout)[idx] = f2b(val);
          } else {  // 3
            ((float*)Cout)[idx] = val;
          }
        }
      }
    }
  }
}

// ---------------------------------------------------------------------------
// scores[bnh][i][j] = (q_i . k_j) * 0.125 ; q,k bf16 [B*S, H] head-sliced
// ---------------------------------------------------------------------------
__global__ __launch_bounds__(256) void scores_kernel(
    const unsigned short* __restrict__ qb, const unsigned short* __restrict__ kb,
    float* __restrict__ attnL)
{
  const int mt = blockIdx.x, nt = blockIdx.y, bnh = blockIdx.z;
  const int b = bnh >> 3, nh = bnh & 7;
  const int tid = threadIdx.x;
  const int w = tid >> 6, lane = tid & 63, lr = lane & 15, lg = lane >> 4;
  const int wm = (w >> 1) * 64, wn = (w & 1) * 64;
  const unsigned short* qbase = qb + (size_t)(b * S_) * H_ + nh * HD_;
  const unsigned short* kbase = kb + (size_t)(b * S_) * H_ + nh * HD_;

  const f32x4 zero4 = {0.f, 0.f, 0.f, 0.f};
  f32x4 acc[4][4];
#pragma unroll
  for (int i = 0; i < 4; i++)
#pragma unroll
    for (int j = 0; j < 4; j++) acc[i][j] = zero4;

#pragma unroll
  for (int ks = 0; ks < 2; ks++) {
    const int k0 = ks * 32 + lg * 8;
    bf16x8 af[4], bfr[4];
#pragma unroll
    for (int mi = 0; mi < 4; mi++)
      af[mi] = *(const bf16x8*)(qbase + (size_t)(mt * 128 + wm + mi * 16 + lr) * H_ + k0);
#pragma unroll
    for (int ni = 0; ni < 4; ni++)
      bfr[ni] = *(const bf16x8*)(kbase + (size_t)(nt * 128 + wn + ni * 16 + lr) * H_ + k0);
#pragma unroll
    for (int mi = 0; mi < 4; mi++)
#pragma unroll
      for (int ni = 0; ni < 4; ni++)
        acc[mi][ni] = __builtin_amdgcn_mfma_f32_16x16x32_bf16(af[mi], bfr[ni], acc[mi][ni], 0, 0, 0);
  }

  float* outp = attnL + (size_t)bnh * S_ * S_;
#pragma unroll
  for (int mi = 0; mi < 4; mi++)
#pragma unroll
    for (int ni = 0; ni < 4; ni++) {
      const int col = nt * 128 + wn + ni * 16 + lr;
#pragma unroll
      for (int r = 0; r < 4; r++) {
        const int row = mt * 128 + wm + mi * 16 + lg * 4 + r;
        outp[(size_t)row * S_ + col] = acc[mi][ni][r] * 0.125f;
      }
    }
}

// ---------------------------------------------------------------------------
// Fused exact top-k threshold (radix select, k=204) + sparse softmax, in-place.
// One 256-thread block per row of 1024 f32.
// ---------------------------------------------------------------------------
__global__ __launch_bounds__(256) void topk_softmax_kernel(float* __restrict__ attnL)
{
  float* p = attnL + (size_t)blockIdx.x * S_;
  const int t = threadIdx.x;
  const int wid = t >> 6, ln_ = t & 63;
  __shared__ int hist[256];
  __shared__ int s_sel, s_above;
  __shared__ float redf[4];

  float4 v4 = ((const float4*)p)[t];
  float vv[4] = {v4.x, v4.y, v4.z, v4.w};
  unsigned int keys[4];
  bool alive[4];
#pragma unroll
  for (int j = 0; j < 4; j++) {
    const unsigned int bb = __float_as_uint(vv[j]);
    keys[j] = (bb & 0x80000000u) ? ~bb : (bb | 0x80000000u);
    alive[j] = true;
  }

  unsigned int prefix = 0;
  int kneed = KTOP_;
  for (int shift = 24; shift >= 0; shift -= 8) {
    hist[t] = 0;
    __syncthreads();
#pragma unroll
    for (int j = 0; j < 4; j++)
      if (alive[j]) atomicAdd(&hist[(keys[j] >> shift) & 0xFF], 1);
    __syncthreads();
    if (wid == 0) {
      const int h0 = hist[ln_ * 4 + 0], h1 = hist[ln_ * 4 + 1];
      const int h2 = hist[ln_ * 4 + 2], h3 = hist[ln_ * 4 + 3];
      const int lsum = h0 + h1 + h2 + h3;
      int sfx = lsum;
#pragma unroll
      for (int offp = 1; offp < 64; offp <<= 1) {
        const int o = __shfl_down(sfx, offp);
        sfx += (ln_ + offp < 64) ? o : 0;
      }
      const int abl = sfx - lsum;  // sum over lanes > ln_
      int cums[4], hs[4] = {h0, h1, h2, h3};
      cums[3] = abl + h3;
      cums[2] = cums[3] + h2;
      cums[1] = cums[2] + h1;
      cums[0] = cums[1] + h0;
#pragma unroll
      for (int j = 0; j < 4; j++) {
        const int above = cums[j] - hs[j];
        if (cums[j] >= kneed && above < kneed) { s_sel = ln_ * 4 + j; s_above = above; }
      }
    }
    __syncthreads();
    const int sel = s_sel;
    kneed -= s_above;
    prefix |= ((unsigned int)sel) << shift;
#pragma unroll
    for (int j = 0; j < 4; j++)
      alive[j] = alive[j] && ((int)((keys[j] >> shift) & 0xFF) == sel);
    __syncthreads();
  }
  const unsigned int fb = (prefix & 0x80000000u) ? (prefix & 0x7fffffffu) : ~prefix;
  const float thresh = __uint_as_float(fb);

  // softmax over entries >= thresh (row max == global max)
  float mx = fmaxf(fmaxf(vv[0], vv[1]), fmaxf(vv[2], vv[3]));
#pragma unroll
  for (int m = 1; m < 64; m <<= 1) mx = fmaxf(mx, __shfl_xor(mx, m));
  if (ln_ == 0) redf[wid] = mx;
  __syncthreads();
  mx = fmaxf(fmaxf(redf[0], redf[1]), fmaxf(redf[2], redf[3]));
  __syncthreads();
  float e[4];
  float ssum = 0.f;
#pragma unroll
  for (int j = 0; j < 4; j++) {
    e[j] = (vv[j] >= thresh) ? expf(vv[j] - mx) : 0.f;
    ssum += e[j];
  }
#pragma unroll
  for (int m = 1; m < 64; m <<= 1) ssum += __shfl_xor(ssum, m);
  if (ln_ == 0) redf[wid] = ssum;
  __syncthreads();
  ssum = redf[0] + redf[1] + redf[2] + redf[3];
  const float inv = 1.0f / ssum;
  ((float4*)p)[t] = make_float4(e[0] * inv, e[1] * inv, e[2] * inv, e[3] * inv);
}

// ---------------------------------------------------------------------------
// o[bnh] = probs(f32, in d_out) @ v ; vt is [B][512][S] bf16 (head-dim rows)
// writes o bf16 [B*S, H] head-interleaved
// ---------------------------------------------------------------------------
__global__ __launch_bounds__(256) void pv_kernel(
    const float* __restrict__ attnL, const unsigned short* __restrict__ vt,
    unsigned short* __restrict__ obf)
{
  const int mt = blockIdx.x, bnh = blockIdx.y;
  const int b = bnh >> 3, nh = bnh & 7;
  const int tid = threadIdx.x;
  const int w = tid >> 6, lane = tid & 63, lr = lane & 15, lg = lane >> 4;
  const float* P = attnL + (size_t)bnh * S_ * S_;
  const unsigned short* vb = vt + (size_t)(b * 512 + nh * HD_) * S_;
  const int rowbase = mt * 128 + w * 32;

  const f32x4 zero4 = {0.f, 0.f, 0.f, 0.f};
  f32x4 acc[2][4];
#pragma unroll
  for (int i = 0; i < 2; i++)
#pragma unroll
    for (int j = 0; j < 4; j++) acc[i][j] = zero4;

  for (int kk = 0; kk < S_; kk += 32) {
    const int k0 = kk + lg * 8;
    bf16x8 af[2];
#pragma unroll
    for (int mi = 0; mi < 2; mi++) {
      const float* pr = P + (size_t)(rowbase + mi * 16 + lr) * S_ + k0;
      const float4 f0 = *(const float4*)pr;
      const float4 f1 = *(const float4*)(pr + 4);
      u16x8 tv;
      tv[0] = f2b(f0.x); tv[1] = f2b(f0.y); tv[2] = f2b(f0.z); tv[3] = f2b(f0.w);
      tv[4] = f2b(f1.x); tv[5] = f2b(f1.y); tv[6] = f2b(f1.z); tv[7] = f2b(f1.w);
      af[mi] = __builtin_bit_cast(bf16x8, tv);
    }
    bf16x8 bfr[4];
#pragma unroll
    for (int ni = 0; ni < 4; ni++)
      bfr[ni] = *(const bf16x8*)(vb + (size_t)(ni * 16 + lr) * S_ + k0);
#pragma unroll
    for (int mi = 0; mi < 2; mi++)
#pragma unroll
      for (int ni = 0; ni < 4; ni++)
        acc[mi][ni] = __builtin_amdgcn_mfma_f32_16x16x32_bf16(af[mi], bfr[ni], acc[mi][ni], 0, 0, 0);
  }

#pragma unroll
  for (int mi = 0; mi < 2; mi++)
#pragma unroll
    for (int ni = 0; ni < 4; ni++) {
      const int col = nh * HD_ + ni * 16 + lr;
#pragma unroll
      for (int r = 0; r < 4; r++) {
        const int row = rowbase + mi * 16 + lg * 4 + r;
        obf[(size_t)(b * S_ + row) * H_ + col] = f2b(acc[mi][ni][r]);
      }
    }
}

// ---------------------------------------------------------------------------
extern "C" void kernel_launch(void* const* d_in, const int* in_sizes, int n_in,
                              void* d_out, int out_size, void* d_ws, size_t ws_size,
                              hipStream_t stream)
{
  (void)in_sizes; (void)n_in; (void)out_size; (void)ws_size;
  const float* x     = (const float*)d_in[0];
  const float* in_w  = (const float*)d_in[1];
  const float* in_b  = (const float*)d_in[2];
  const float* ln1_g = (const float*)d_in[3];
  const float* ln1_b = (const float*)d_in[4];
  const float* qw    = (const float*)d_in[5];
  const float* qbias = (const float*)d_in[6];
  const float* kw    = (const float*)d_in[7];
  const float* kbias = (const float*)d_in[8];
  const float* vw    = (const float*)d_in[9];
  const float* vbias = (const float*)d_in[10];
  const float* ow    = (const float*)d_in[11];
  const float* obias = (const float*)d_in[12];
  const float* ln2_g = (const float*)d_in[13];
  const float* ln2_b = (const float*)d_in[14];
  const float* w1    = (const float*)d_in[15];
  const float* b1    = (const float*)d_in[16];
  const float* w2    = (const float*)d_in[17];
  const float* b2    = (const float*)d_in[18];
  const float* fn_g  = (const float*)d_in[19];
  const float* fn_b  = (const float*)d_in[20];
  const float* out_w = (const float*)d_in[21];
  const float* out_b = (const float*)d_in[22];

  char* ws = (char*)d_ws;
  size_t off = 0;
  auto alloc = [&](size_t bytes) -> void* {
    void* p = ws + off;
    off += (bytes + 255) & ~(size_t)255;
    return p;
  };
  float* h           = (float*)alloc((size_t)BS_ * H_ * 4);
  unsigned short* Wqt = (unsigned short*)alloc((size_t)L_ * H_ * H_ * 2);
  unsigned short* Wkt = (unsigned short*)alloc((size_t)L_ * H_ * H_ * 2);
  unsigned short* Wvt = (unsigned short*)alloc((size_t)L_ * H_ * H_ * 2);
  unsigned short* Wot = (unsigned short*)alloc((size_t)L_ * H_ * H_ * 2);
  unsigned short* W1t = (unsigned short*)alloc((size_t)L_ * MLP_ * H_ * 2);
  unsigned short* W2t = (unsigned short*)alloc((size_t)L_ * H_ * MLP_ * 2);
  unsigned short* OWt = (unsigned short*)alloc((size_t)OUT_ * H_ * 2);
  unsigned short* nbf = (unsigned short*)alloc((size_t)BS_ * H_ * 2);
  unsigned short* qbf = (unsigned short*)alloc((size_t)BS_ * H_ * 2);
  unsigned short* kbf = (unsigned short*)alloc((size_t)BS_ * H_ * 2);
  unsigned short* vtb = (unsigned short*)alloc((size_t)B_ * 512 * S_ * 2);
  unsigned short* obf = (unsigned short*)alloc((size_t)BS_ * H_ * 2);
  unsigned short* tbf = (unsigned short*)alloc((size_t)BS_ * MLP_ * 2);

  float* attn_base = (float*)d_out + (size_t)BS_ * OUT_;

  const dim3 tb(256);
  transpose_conv_kernel<<<dim3(16, 16, 4), tb, 0, stream>>>(qw, Wqt, H_, H_);
  transpose_conv_kernel<<<dim3(16, 16, 4), tb, 0, stream>>>(kw, Wkt, H_, H_);
  transpose_conv_kernel<<<dim3(16, 16, 4), tb, 0, stream>>>(vw, Wvt, H_, H_);
  transpose_conv_kernel<<<dim3(16, 16, 4), tb, 0, stream>>>(ow, Wot, H_, H_);
  transpose_conv_kernel<<<dim3(64, 16, 4), tb, 0, stream>>>(w1, W1t, H_, MLP_);
  transpose_conv_kernel<<<dim3(16, 64, 4), tb, 0, stream>>>(w2, W2t, MLP_, H_);
  transpose_conv_kernel<<<dim3(4, 16, 1),  tb, 0, stream>>>(out_w, OWt, H_, OUT_);

  input_pe_kernel<<<dim3(BS_), dim3(128), 0, stream>>>(x, in_w, in_b, h);

  for (int l = 0; l < L_; l++) {
    float* attnL = attn_base + (size_t)l * 16 * S_ * S_;
    ln_kernel<<<dim3(BS_), dim3(128), 0, stream>>>(h, ln1_g + l * H_, ln1_b + l * H_, nbf);
    gemm_kernel<0><<<dim3(16, 4), tb, 0, stream>>>(nbf, Wqt + (size_t)l * H_ * H_, qbias + l * H_, qbf, BS_, H_, H_);
    gemm_kernel<0><<<dim3(16, 4), tb, 0, stream>>>(nbf, Wkt + (size_t)l * H_ * H_, kbias + l * H_, kbf, BS_, H_, H_);
    gemm_kernel<4><<<dim3(16, 4), tb, 0, stream>>>(nbf, Wvt + (size_t)l * H_ * H_, vbias + l * H_, vtb, BS_, H_, H_);
    scores_kernel<<<dim3(8, 8, 16), tb, 0, stream>>>(qbf, kbf, attnL);
    topk_softmax_kernel<<<dim3(16 * S_), tb, 0, stream>>>(attnL);
    pv_kernel<<<dim3(8, 16), tb, 0, stream>>>(attnL, vtb, obf);
    gemm_kernel<1><<<dim3(16, 4), tb, 0, stream>>>(obf, Wot + (size_t)l * H_ * H_, obias + l * H_, h, BS_, H_, H_);
    ln_kernel<<<dim3(BS_), dim3(128), 0, stream>>>(h, ln2_g + l * H_, ln2_b + l * H_, nbf);
    gemm_kernel<2><<<dim3(16, 16), tb, 0, stream>>>(nbf, W1t + (size_t)l * MLP_ * H_, b1 + l * MLP_, tbf, BS_, MLP_, H_);
    gemm_kernel<1><<<dim3(16, 4), tb, 0, stream>>>(tbf, W2t + (size_t)l * H_ * MLP_, b2 + l * H_, h, BS_, H_, MLP_);
  }

  ln_kernel<<<dim3(BS_), dim3(128), 0, stream>>>(h, fn_g, fn_b, nbf);
  gemm_kernel<3><<<dim3(16, 1), tb, 0, stream>>>(nbf, OWt, out_b, d_out, BS_, OUT_, H_);
}

// Round 2
// 1304.420 us; speedup vs baseline: 1.0341x; 1.0341x over previous
//
#include <hip/hip_runtime.h>
#include <math.h>

#define DEVINL __device__ __forceinline__

constexpr int S_   = 1024;
constexpr int H_   = 512;
constexpr int NH_  = 8;
constexpr int L_   = 4;
constexpr int HD_  = 64;
constexpr int MLP_ = 2048;
constexpr int OUT_ = 128;
constexpr int B_   = 2;
constexpr int BS_  = 2048;   // B*S
constexpr int KTOP_ = 204;

typedef __bf16 bf16x8 __attribute__((ext_vector_type(8)));
typedef float f32x4 __attribute__((ext_vector_type(4)));

DEVINL unsigned short f2b(float f) {
  unsigned int u = __float_as_uint(f);
  unsigned int r = (u + 0x7fffu + ((u >> 16) & 1u)) >> 16;  // RNE
  return (unsigned short)r;
}

// ---------------------------------------------------------------------------
// Generic transpose + f32->bf16 convert: src f32 [z][R][C] -> dst bf16 [z][C][R]
// ---------------------------------------------------------------------------
__global__ __launch_bounds__(256) void transpose_conv_kernel(
    const float* __restrict__ src, unsigned short* __restrict__ dst, int R, int C)
{
  __shared__ float tile[32][33];
  const size_t base = (size_t)blockIdx.z * R * C;
  src += base; dst += base;
  const int c0 = blockIdx.x * 32;
  const int r0 = blockIdx.y * 32;
  const int tx = threadIdx.x & 31;
  const int ty = threadIdx.x >> 5;   // 0..7
#pragma unroll
  for (int j = 0; j < 4; j++)
    tile[ty + j * 8][tx] = src[(size_t)(r0 + ty + j * 8) * C + c0 + tx];
  __syncthreads();
#pragma unroll
  for (int j = 0; j < 4; j++)
    dst[(size_t)(c0 + ty + j * 8) * R + r0 + tx] = f2b(tile[tx][ty + j * 8]);
}

// ---------------------------------------------------------------------------
// Batched transpose of the four [L][512][512] weights.
// q/k/v go into Wqkvt [L][1536][512] (row blocks 0/512/1024), o -> Wot.
// grid (16,16,16): z = which*4 + layer
// ---------------------------------------------------------------------------
__global__ __launch_bounds__(256) void transpose_qkvo_kernel(
    const float* __restrict__ qw, const float* __restrict__ kw,
    const float* __restrict__ vw, const float* __restrict__ ow,
    unsigned short* __restrict__ qkv, unsigned short* __restrict__ ot)
{
  __shared__ float tile[32][33];
  const int z = blockIdx.z;
  const int which = z >> 2, l = z & 3;
  const float* src = (which == 0 ? qw : which == 1 ? kw : which == 2 ? vw : ow)
                     + (size_t)l * 512 * 512;
  unsigned short* dst = (which < 3)
      ? (qkv + (size_t)l * 1536 * 512 + (size_t)which * 512 * 512)
      : (ot + (size_t)l * 512 * 512);
  const int c0 = blockIdx.x * 32;
  const int r0 = blockIdx.y * 32;
  const int tx = threadIdx.x & 31;
  const int ty = threadIdx.x >> 5;
#pragma unroll
  for (int j = 0; j < 4; j++)
    tile[ty + j * 8][tx] = src[(size_t)(r0 + ty + j * 8) * 512 + c0 + tx];
  __syncthreads();
#pragma unroll
  for (int j = 0; j < 4; j++)
    dst[(size_t)(c0 + ty + j * 8) * 512 + r0 + tx] = f2b(tile[tx][ty + j * 8]);
}

// ---------------------------------------------------------------------------
// h[b,s,:] = x[b,s]*in_w + in_b + pos_encoding(s,:)
// ---------------------------------------------------------------------------
__global__ __launch_bounds__(128) void input_pe_kernel(
    const float* __restrict__ x, const float* __restrict__ in_w,
    const float* __restrict__ in_b, float* __restrict__ h)
{
  const int row = blockIdx.x;          // 0..2047
  const int s = row & (S_ - 1);
  const int c = threadIdx.x * 4;
  const float xv = x[row];
  const float4 wv = *(const float4*)(in_w + c);
  const float4 bv = *(const float4*)(in_b + c);
  const float* wp = (const float*)&wv;
  const float* bp = (const float*)&bv;
  float o[4];
#pragma unroll
  for (int j = 0; j < 4; j++) {
    const int cc = c + j;
    const float di = expf(-(float)(cc & ~1) * (9.210340371976184f / 512.0f));
    const float ang = (float)s * di;
    const float pe = (cc & 1) ? cosf(ang) : sinf(ang);
    o[j] = xv * wp[j] + bp[j] + pe;
  }
  *(float4*)(h + (size_t)row * H_ + c) = make_float4(o[0], o[1], o[2], o[3]);
}

// ---------------------------------------------------------------------------
// LayerNorm: f32 in -> bf16 out (row = 512)
// ---------------------------------------------------------------------------
__global__ __launch_bounds__(128) void ln_kernel(
    const float* __restrict__ hin, const float* __restrict__ g,
    const float* __restrict__ b, unsigned short* __restrict__ nout)
{
  const int row = blockIdx.x;
  const int t = threadIdx.x;
  const int wid = t >> 6, ln_ = t & 63;
  __shared__ float red[2];
  float4 v = ((const float4*)(hin + (size_t)row * H_))[t];
  float sm = v.x + v.y + v.z + v.w;
#pragma unroll
  for (int m = 1; m < 64; m <<= 1) sm += __shfl_xor(sm, m);
  if (ln_ == 0) red[wid] = sm;
  __syncthreads();
  const float mean = (red[0] + red[1]) * (1.0f / 512.0f);
  __syncthreads();
  const float dx = v.x - mean, dy = v.y - mean, dz = v.z - mean, dw = v.w - mean;
  float ss = dx * dx + dy * dy + dz * dz + dw * dw;
#pragma unroll
  for (int m = 1; m < 64; m <<= 1) ss += __shfl_xor(ss, m);
  if (ln_ == 0) red[wid] = ss;
  __syncthreads();
  const float var = (red[0] + red[1]) * (1.0f / 512.0f);
  const float rs = rsqrtf(var + 1e-5f);
  const float4 gv = ((const float4*)g)[t];
  const float4 bv = ((const float4*)b)[t];
  ushort4 o;
  o.x = f2b(dx * rs * gv.x + bv.x);
  o.y = f2b(dy * rs * gv.y + bv.y);
  o.z = f2b(dz * rs * gv.z + bv.z);
  o.w = f2b(dw * rs * gv.w + bv.w);
  ((ushort4*)(nout + (size_t)row * H_))[t] = o;
}

// ---------------------------------------------------------------------------
// GEMM: C[M,N] = epi(A[M,K](bf16) @ Bt[N,K]^T(bf16) + bias[N])
// EPI: 1 = f32 out += (residual in-place), 2 = gelu -> bf16, 3 = f32 out,
//      5 = fused QKV epilogue: col<512 -> q (scaled 0.125, bf16),
//          col<1024 -> k (bf16), else -> v transposed into vt[B][512][S]
// 128x128 tile, BK=32, 4 waves (2x2 of 64x64), mfma_f32_16x16x32_bf16
// ---------------------------------------------------------------------------
template <int EPI>
__global__ __launch_bounds__(256, 2) void gemm_kernel(
    const unsigned short* __restrict__ A, const unsigned short* __restrict__ Bt,
    const float* __restrict__ bias, void* __restrict__ Cout, int M, int N, int K,
    const float* __restrict__ bias2, const float* __restrict__ bias3,
    void* __restrict__ C2, void* __restrict__ C3)
{
  constexpr int LDK = 56;   // padded LDS stride
  __shared__ unsigned short Alds[128 * LDK];
  __shared__ unsigned short Blds[128 * LDK];
  const int tid = threadIdx.x;
  const int w = tid >> 6, lane = tid & 63, lr = lane & 15, lg = lane >> 4;
  const int m0 = blockIdx.x * 128, n0 = blockIdx.y * 128;
  const int wm = (w >> 1) * 64, wn = (w & 1) * 64;

  const int e0 = tid * 8;
  const int r0 = e0 >> 5, c0 = e0 & 31;
  const unsigned short* Ap0 = A + (size_t)(m0 + r0) * K + c0;
  const unsigned short* Ap1 = Ap0 + (size_t)64 * K;
  const unsigned short* Bp0 = Bt + (size_t)(n0 + r0) * K + c0;
  const unsigned short* Bp1 = Bp0 + (size_t)64 * K;
  unsigned short* AL0 = Alds + r0 * LDK + c0;
  unsigned short* AL1 = AL0 + 64 * LDK;
  unsigned short* BL0 = Blds + r0 * LDK + c0;
  unsigned short* BL1 = BL0 + 64 * LDK;

  const f32x4 zero4 = {0.f, 0.f, 0.f, 0.f};
  f32x4 acc[4][4];
#pragma unroll
  for (int i = 0; i < 4; i++)
#pragma unroll
    for (int j = 0; j < 4; j++) acc[i][j] = zero4;

  for (int kt = 0; kt < K; kt += 32) {
    const int4 a0 = *(const int4*)(Ap0 + kt);
    const int4 a1 = *(const int4*)(Ap1 + kt);
    const int4 b0 = *(const int4*)(Bp0 + kt);
    const int4 b1 = *(const int4*)(Bp1 + kt);
    __syncthreads();
    *(int4*)AL0 = a0; *(int4*)AL1 = a1;
    *(int4*)BL0 = b0; *(int4*)BL1 = b1;
    __syncthreads();
    bf16x8 af[4], bfr[4];
#pragma unroll
    for (int mi = 0; mi < 4; mi++)
      af[mi] = *(const bf16x8*)(Alds + (wm + mi * 16 + lr) * LDK + lg * 8);
#pragma unroll
    for (int ni = 0; ni < 4; ni++)
      bfr[ni] = *(const bf16x8*)(Blds + (wn + ni * 16 + lr) * LDK + lg * 8);
#pragma unroll
    for (int mi = 0; mi < 4; mi++)
#pragma unroll
      for (int ni = 0; ni < 4; ni++)
        acc[mi][ni] = __builtin_amdgcn_mfma_f32_16x16x32_bf16(af[mi], bfr[ni], acc[mi][ni], 0, 0, 0);
  }

#pragma unroll
  for (int mi = 0; mi < 4; mi++) {
#pragma unroll
    for (int ni = 0; ni < 4; ni++) {
      const int col = n0 + wn + ni * 16 + lr;
      if constexpr (EPI == 5) {
        if (col < 512) {
          const float bs = bias[col];
#pragma unroll
          for (int r = 0; r < 4; r++) {
            const int row = m0 + wm + mi * 16 + lg * 4 + r;
            ((unsigned short*)Cout)[(size_t)row * 512 + col] =
                f2b((acc[mi][ni][r] + bs) * 0.125f);
          }
        } else if (col < 1024) {
          const float bs = bias2[col - 512];
#pragma unroll
          for (int r = 0; r < 4; r++) {
            const int row = m0 + wm + mi * 16 + lg * 4 + r;
            ((unsigned short*)C2)[(size_t)row * 512 + (col - 512)] =
                f2b(acc[mi][ni][r] + bs);
          }
        } else {
          const float bs = bias3[col - 1024];
          const int row0_ = m0 + wm + mi * 16 + lg * 4;
          const int bb = row0_ >> 10, ssi = row0_ & 1023;
          ushort4 pk;
          pk.x = f2b(acc[mi][ni][0] + bs);
          pk.y = f2b(acc[mi][ni][1] + bs);
          pk.z = f2b(acc[mi][ni][2] + bs);
          pk.w = f2b(acc[mi][ni][3] + bs);
          *(ushort4*)((unsigned short*)C3 + ((size_t)(bb * 512 + (col - 1024))) * 1024 + ssi) = pk;
        }
      } else {
        const float bs = bias[col];
#pragma unroll
        for (int r = 0; r < 4; r++) {
          const int row = m0 + wm + mi * 16 + lg * 4 + r;
          float val = acc[mi][ni][r] + bs;
          const size_t idx = (size_t)row * N + col;
          if constexpr (EPI == 1) {
            ((float*)Cout)[idx] += val;
          } else if constexpr (EPI == 2) {
            val = 0.5f * val * (1.0f + erff(val * 0.7071067811865475f));
            ((unsigned short*)Cout)[idx] = f2b(val);
          } else {  // 3
            ((float*)Cout)[idx] = val;
          }
        }
      }
    }
  }
}

// ---------------------------------------------------------------------------
// Fused attention: scores (MFMA, K*Q^T swapped) -> LDS -> exact radix top-k +
// softmax (wave-local, in-register) -> probs f32 to d_out + bf16 in LDS ->
// PV (MFMA, split-K across waves) -> o bf16.
// Block: 256 threads, 32 q-rows of one (b,nh). Grid (S/32, B*NH).
// q is pre-scaled by 0.125 in the QKV epilogue.
// ---------------------------------------------------------------------------
__global__ __launch_bounds__(256, 1) void attn_fused_kernel(
    const unsigned short* __restrict__ qbf, const unsigned short* __restrict__ kbf,
    const unsigned short* __restrict__ vt, float* __restrict__ attnL,
    unsigned short* __restrict__ obf)
{
  constexpr int LDF = 1032;                 // padded f32 row stride
  __shared__ float sc[32 * LDF];            // 132 KB
  __shared__ int hist[4][256];              // 4 KB (per-wave histograms)
  const int mblk = blockIdx.x, bnh = blockIdx.y;
  const int b = bnh >> 3, nh = bnh & 7;
  const int tid = threadIdx.x, w = tid >> 6, lane = tid & 63;
  const int lr = lane & 15, lg = lane >> 4;
  const int row0 = mblk * 32;

  const unsigned short* qbase = qbf + ((size_t)(b * S_ + row0)) * H_ + nh * HD_;
  const unsigned short* kbase = kbf + (size_t)(b * S_) * H_ + nh * HD_;

  // ---- Phase 1: scores. mfma(K-rows, Q-rows): acc regs run along k ----
  const f32x4 zero4 = {0.f, 0.f, 0.f, 0.f};
  {
    f32x4 acc[16][2];
#pragma unroll
    for (int kt = 0; kt < 16; kt++) { acc[kt][0] = zero4; acc[kt][1] = zero4; }
    bf16x8 qf[2][2];
#pragma unroll
    for (int qt = 0; qt < 2; qt++)
#pragma unroll
      for (int ks = 0; ks < 2; ks++)
        qf[qt][ks] = *(const bf16x8*)(qbase + (size_t)(qt * 16 + lr) * H_ + ks * 32 + lg * 8);
    const int kw0 = w * 256;
#pragma unroll
    for (int kt = 0; kt < 16; kt++) {
      const unsigned short* kp = kbase + (size_t)(kw0 + kt * 16 + lr) * H_ + lg * 8;
      const bf16x8 kf0 = *(const bf16x8*)(kp);
      const bf16x8 kf1 = *(const bf16x8*)(kp + 32);
#pragma unroll
      for (int qt = 0; qt < 2; qt++) {
        acc[kt][qt] = __builtin_amdgcn_mfma_f32_16x16x32_bf16(kf0, qf[qt][0], acc[kt][qt], 0, 0, 0);
        acc[kt][qt] = __builtin_amdgcn_mfma_f32_16x16x32_bf16(kf1, qf[qt][1], acc[kt][qt], 0, 0, 0);
      }
    }
#pragma unroll
    for (int kt = 0; kt < 16; kt++)
#pragma unroll
      for (int qt = 0; qt < 2; qt++)
        *(f32x4*)(sc + (size_t)(qt * 16 + lr) * LDF + kw0 + kt * 16 + lg * 4) = acc[kt][qt];
  }
  __syncthreads();

  // ---- Phase 2: per-row exact top-k threshold + softmax (wave w: rows w*8..) ----
  for (int rr = 0; rr < 8; rr++) {
    const int row = w * 8 + rr;
    float* rowp = sc + (size_t)row * LDF;
    float v[16];
#pragma unroll
    for (int j = 0; j < 8; j++) {
      const float2 t2 = *(const float2*)(rowp + 2 * lane + j * 128);
      v[2 * j] = t2.x; v[2 * j + 1] = t2.y;
    }
    unsigned int keys[16];
#pragma unroll
    for (int j = 0; j < 16; j++) {
      const unsigned int u = __float_as_uint(v[j]);
      keys[j] = (u & 0x80000000u) ? ~u : (u | 0x80000000u);
    }
    unsigned int alivem = 0xFFFFu;
    unsigned int prefix = 0;
    int kneed = KTOP_;
#pragma unroll
    for (int shift = 24; shift >= 0; shift -= 8) {
      *(int4*)&hist[w][lane * 4] = make_int4(0, 0, 0, 0);
#pragma unroll
      for (int j = 0; j < 16; j++)
        if (alivem & (1u << j)) atomicAdd(&hist[w][(keys[j] >> shift) & 0xFF], 1);
      const int4 h4 = *(const int4*)&hist[w][lane * 4];
      const int hs[4] = {h4.x, h4.y, h4.z, h4.w};
      const int lsum = hs[0] + hs[1] + hs[2] + hs[3];
      int sfx = lsum;
#pragma unroll
      for (int offp = 1; offp < 64; offp <<= 1) {
        const int o = __shfl_down(sfx, offp);
        sfx += (lane + offp < 64) ? o : 0;
      }
      const int abl = sfx - lsum;  // count in lanes > me
      int cums[4];
      cums[3] = abl + hs[3];
      cums[2] = cums[3] + hs[2];
      cums[1] = cums[2] + hs[1];
      cums[0] = cums[1] + hs[0];
      int sel = -1, abv = 0;
#pragma unroll
      for (int jj = 0; jj < 4; jj++) {
        const int above = cums[jj] - hs[jj];
        if (cums[jj] >= kneed && above < kneed) { sel = lane * 4 + jj; abv = above; }
      }
      const unsigned long long mball = __ballot(sel >= 0);
      const int srcl = __ffsll((unsigned long long)mball) - 1;
      sel = __shfl(sel, srcl);
      abv = __shfl(abv, srcl);
      kneed -= abv;
      prefix |= ((unsigned int)sel) << shift;
      unsigned int na = 0;
#pragma unroll
      for (int j = 0; j < 16; j++)
        if (((alivem >> j) & 1u) && ((int)((keys[j] >> shift) & 0xFF) == sel)) na |= (1u << j);
      alivem = na;
    }
    const unsigned int fb = (prefix & 0x80000000u) ? (prefix & 0x7fffffffu) : ~prefix;
    const float thresh = __uint_as_float(fb);

    float mx = v[0];
#pragma unroll
    for (int j = 1; j < 16; j++) mx = fmaxf(mx, v[j]);
#pragma unroll
    for (int m = 1; m < 64; m <<= 1) mx = fmaxf(mx, __shfl_xor(mx, m));
    float p[16];
    float ssum = 0.f;
#pragma unroll
    for (int j = 0; j < 16; j++) {
      const float e = expf(v[j] - mx);
      p[j] = (v[j] >= thresh) ? e : 0.f;
      ssum += p[j];
    }
#pragma unroll
    for (int m = 1; m < 64; m <<= 1) ssum += __shfl_xor(ssum, m);
    const float inv = 1.0f / ssum;
    float* outrow = attnL + (size_t)bnh * S_ * S_ + (size_t)(row0 + row) * S_;
    unsigned short* prow = (unsigned short*)rowp;
#pragma unroll
    for (int j = 0; j < 8; j++) {
      const float p0 = p[2 * j] * inv, p1 = p[2 * j + 1] * inv;
      *(float2*)(outrow + 2 * lane + j * 128) = make_float2(p0, p1);
      const unsigned int pk = ((unsigned int)f2b(p1) << 16) | (unsigned int)f2b(p0);
      *(unsigned int*)(prow + 2 * lane + j * 128) = pk;
    }
  }
  __syncthreads();

  // ---- Phase 3: PV, split-K across waves ----
  const unsigned short* vb = vt + (size_t)(b * 512 + nh * HD_) * S_;
  f32x4 oacc[2][4];
#pragma unroll
  for (int mi = 0; mi < 2; mi++)
#pragma unroll
    for (int ni = 0; ni < 4; ni++) oacc[mi][ni] = zero4;
  const unsigned short* scu = (const unsigned short*)sc;
#pragma unroll
  for (int ks = 0; ks < 8; ks++) {
    const int k0 = w * 256 + ks * 32;
    bf16x8 pf[2];
#pragma unroll
    for (int mi = 0; mi < 2; mi++)
      pf[mi] = *(const bf16x8*)(scu + (size_t)(mi * 16 + lr) * (2 * LDF) + k0 + lg * 8);
    bf16x8 vfr[4];
#pragma unroll
    for (int ni = 0; ni < 4; ni++)
      vfr[ni] = *(const bf16x8*)(vb + (size_t)(ni * 16 + lr) * S_ + k0 + lg * 8);
#pragma unroll
    for (int mi = 0; mi < 2; mi++)
#pragma unroll
      for (int ni = 0; ni < 4; ni++)
        oacc[mi][ni] = __builtin_amdgcn_mfma_f32_16x16x32_bf16(pf[mi], vfr[ni], oacc[mi][ni], 0, 0, 0);
  }
  __syncthreads();   // all waves done reading probs before overwrite
  float* red = sc + w * 2048;   // [32][64] partial per wave
#pragma unroll
  for (int mi = 0; mi < 2; mi++)
#pragma unroll
    for (int ni = 0; ni < 4; ni++)
#pragma unroll
      for (int r = 0; r < 4; r++)
        red[(mi * 16 + lg * 4 + r) * 64 + ni * 16 + lr] = oacc[mi][ni][r];
  __syncthreads();
  {
    const int orow = tid >> 3, oc0 = (tid & 7) * 8;
    const float* rp = sc + orow * 64 + oc0;
    float4 s0 = *(const float4*)(rp) ;
    float4 t0 = *(const float4*)(rp + 4);
#pragma unroll
    for (int ww = 1; ww < 4; ww++) {
      const float4 a = *(const float4*)(rp + ww * 2048);
      const float4 c = *(const float4*)(rp + ww * 2048 + 4);
      s0.x += a.x; s0.y += a.y; s0.z += a.z; s0.w += a.w;
      t0.x += c.x; t0.y += c.y; t0.z += c.z; t0.w += c.w;
    }
    ushort4 o1, o2;
    o1.x = f2b(s0.x); o1.y = f2b(s0.y); o1.z = f2b(s0.z); o1.w = f2b(s0.w);
    o2.x = f2b(t0.x); o2.y = f2b(t0.y); o2.z = f2b(t0.z); o2.w = f2b(t0.w);
    unsigned short* dst = obf + (size_t)(b * S_ + row0 + orow) * H_ + nh * HD_ + oc0;
    *(ushort4*)dst = o1;
    *(ushort4*)(dst + 4) = o2;
  }
}

// ---------------------------------------------------------------------------
extern "C" void kernel_launch(void* const* d_in, const int* in_sizes, int n_in,
                              void* d_out, int out_size, void* d_ws, size_t ws_size,
                              hipStream_t stream)
{
  (void)in_sizes; (void)n_in; (void)out_size; (void)ws_size;
  const float* x     = (const float*)d_in[0];
  const float* in_w  = (const float*)d_in[1];
  const float* in_b  = (const float*)d_in[2];
  const float* ln1_g = (const float*)d_in[3];
  const float* ln1_b = (const float*)d_in[4];
  const float* qw    = (const float*)d_in[5];
  const float* qbias = (const float*)d_in[6];
  const float* kw    = (const float*)d_in[7];
  const float* kbias = (const float*)d_in[8];
  const float* vw    = (const float*)d_in[9];
  const float* vbias = (const float*)d_in[10];
  const float* ow    = (const float*)d_in[11];
  const float* obias = (const float*)d_in[12];
  const float* ln2_g = (const float*)d_in[13];
  const float* ln2_b = (const float*)d_in[14];
  const float* w1    = (const float*)d_in[15];
  const float* b1    = (const float*)d_in[16];
  const float* w2    = (const float*)d_in[17];
  const float* b2    = (const float*)d_in[18];
  const float* fn_g  = (const float*)d_in[19];
  const float* fn_b  = (const float*)d_in[20];
  const float* out_w = (const float*)d_in[21];
  const float* out_b = (const float*)d_in[22];

  char* ws = (char*)d_ws;
  size_t off = 0;
  auto alloc = [&](size_t bytes) -> void* {
    void* p = ws + off;
    off += (bytes + 255) & ~(size_t)255;
    return p;
  };
  float* h             = (float*)alloc((size_t)BS_ * H_ * 4);
  unsigned short* Wqkvt = (unsigned short*)alloc((size_t)L_ * 1536 * H_ * 2);
  unsigned short* Wot  = (unsigned short*)alloc((size_t)L_ * H_ * H_ * 2);
  unsigned short* W1t  = (unsigned short*)alloc((size_t)L_ * MLP_ * H_ * 2);
  unsigned short* W2t  = (unsigned short*)alloc((size_t)L_ * H_ * MLP_ * 2);
  unsigned short* OWt  = (unsigned short*)alloc((size_t)OUT_ * H_ * 2);
  unsigned short* nbf  = (unsigned short*)alloc((size_t)BS_ * H_ * 2);
  unsigned short* qbf  = (unsigned short*)alloc((size_t)BS_ * H_ * 2);
  unsigned short* kbf  = (unsigned short*)alloc((size_t)BS_ * H_ * 2);
  unsigned short* vtb  = (unsigned short*)alloc((size_t)B_ * 512 * S_ * 2);
  unsigned short* obf  = (unsigned short*)alloc((size_t)BS_ * H_ * 2);
  unsigned short* tbf  = (unsigned short*)alloc((size_t)BS_ * MLP_ * 2);

  float* attn_base = (float*)d_out + (size_t)BS_ * OUT_;

  const dim3 tb(256);
  transpose_qkvo_kernel<<<dim3(16, 16, 16), tb, 0, stream>>>(qw, kw, vw, ow, Wqkvt, Wot);
  transpose_conv_kernel<<<dim3(64, 16, 4), tb, 0, stream>>>(w1, W1t, H_, MLP_);
  transpose_conv_kernel<<<dim3(16, 64, 4), tb, 0, stream>>>(w2, W2t, MLP_, H_);
  transpose_conv_kernel<<<dim3(4, 16, 1),  tb, 0, stream>>>(out_w, OWt, H_, OUT_);

  input_pe_kernel<<<dim3(BS_), dim3(128), 0, stream>>>(x, in_w, in_b, h);

  for (int l = 0; l < L_; l++) {
    float* attnL = attn_base + (size_t)l * 16 * S_ * S_;
    ln_kernel<<<dim3(BS_), dim3(128), 0, stream>>>(h, ln1_g + l * H_, ln1_b + l * H_, nbf);
    gemm_kernel<5><<<dim3(16, 12), tb, 0, stream>>>(
        nbf, Wqkvt + (size_t)l * 1536 * H_, qbias + l * H_, qbf, BS_, 1536, H_,
        kbias + l * H_, vbias + l * H_, kbf, vtb);
    attn_fused_kernel<<<dim3(32, 16), tb, 0, stream>>>(qbf, kbf, vtb, attnL, obf);
    gemm_kernel<1><<<dim3(16, 4), tb, 0, stream>>>(
        obf, Wot + (size_t)l * H_ * H_, obias + l * H_, h, BS_, H_, H_,
        nullptr, nullptr, nullptr, nullptr);
    ln_kernel<<<dim3(BS_), dim3(128), 0, stream>>>(h, ln2_g + l * H_, ln2_b + l * H_, nbf);
    gemm_kernel<2><<<dim3(16, 16), tb, 0, stream>>>(
        nbf, W1t + (size_t)l * MLP_ * H_, b1 + l * MLP_, tbf, BS_, MLP_, H_,
        nullptr, nullptr, nullptr, nullptr);
    gemm_kernel<1><<<dim3(16, 4), tb, 0, stream>>>(
        tbf, W2t + (size_t)l * H_ * MLP_, b2 + l * H_, h, BS_, H_, MLP_,
        nullptr, nullptr, nullptr, nullptr);
  }

  ln_kernel<<<dim3(BS_), dim3(128), 0, stream>>>(h, fn_g, fn_b, nbf);
  gemm_kernel<3><<<dim3(16, 1), tb, 0, stream>>>(
      nbf, OWt, out_b, d_out, BS_, OUT_, H_,
      nullptr, nullptr, nullptr, nullptr);
}

// Round 4
// 1193.977 us; speedup vs baseline: 1.1298x; 1.0925x over previous
//
#include <hip/hip_runtime.h>
#include <math.h>

#define DEVINL __device__ __forceinline__

constexpr int S_   = 1024;
constexpr int H_   = 512;
constexpr int NH_  = 8;
constexpr int L_   = 4;
constexpr int HD_  = 64;
constexpr int MLP_ = 2048;
constexpr int OUT_ = 128;
constexpr int B_   = 2;
constexpr int BS_  = 2048;   // B*S
constexpr int KTOP_ = 204;

typedef __bf16 bf16x8 __attribute__((ext_vector_type(8)));
typedef float f32x4 __attribute__((ext_vector_type(4)));

DEVINL unsigned short f2b(float f) {
  unsigned int u = __float_as_uint(f);
  unsigned int r = (u + 0x7fffu + ((u >> 16) & 1u)) >> 16;  // RNE
  return (unsigned short)r;
}

// ---------------------------------------------------------------------------
// Generic transpose + f32->bf16 convert: src f32 [z][R][C] -> dst bf16 [z][C][R]
// ---------------------------------------------------------------------------
__global__ __launch_bounds__(256) void transpose_conv_kernel(
    const float* __restrict__ src, unsigned short* __restrict__ dst, int R, int C)
{
  __shared__ float tile[32][33];
  const size_t base = (size_t)blockIdx.z * R * C;
  src += base; dst += base;
  const int c0 = blockIdx.x * 32;
  const int r0 = blockIdx.y * 32;
  const int tx = threadIdx.x & 31;
  const int ty = threadIdx.x >> 5;   // 0..7
#pragma unroll
  for (int j = 0; j < 4; j++)
    tile[ty + j * 8][tx] = src[(size_t)(r0 + ty + j * 8) * C + c0 + tx];
  __syncthreads();
#pragma unroll
  for (int j = 0; j < 4; j++)
    dst[(size_t)(c0 + ty + j * 8) * R + r0 + tx] = f2b(tile[tx][ty + j * 8]);
}

// ---------------------------------------------------------------------------
// Batched transpose of the four [L][512][512] weights.
// q/k/v go into Wqkvt [L][1536][512] (row blocks 0/512/1024), o -> Wot.
// grid (16,16,16): z = which*4 + layer
// ---------------------------------------------------------------------------
__global__ __launch_bounds__(256) void transpose_qkvo_kernel(
    const float* __restrict__ qw, const float* __restrict__ kw,
    const float* __restrict__ vw, const float* __restrict__ ow,
    unsigned short* __restrict__ qkv, unsigned short* __restrict__ ot)
{
  __shared__ float tile[32][33];
  const int z = blockIdx.z;
  const int which = z >> 2, l = z & 3;
  const float* src = (which == 0 ? qw : which == 1 ? kw : which == 2 ? vw : ow)
                     + (size_t)l * 512 * 512;
  unsigned short* dst = (which < 3)
      ? (qkv + (size_t)l * 1536 * 512 + (size_t)which * 512 * 512)
      : (ot + (size_t)l * 512 * 512);
  const int c0 = blockIdx.x * 32;
  const int r0 = blockIdx.y * 32;
  const int tx = threadIdx.x & 31;
  const int ty = threadIdx.x >> 5;
#pragma unroll
  for (int j = 0; j < 4; j++)
    tile[ty + j * 8][tx] = src[(size_t)(r0 + ty + j * 8) * 512 + c0 + tx];
  __syncthreads();
#pragma unroll
  for (int j = 0; j < 4; j++)
    dst[(size_t)(c0 + ty + j * 8) * 512 + r0 + tx] = f2b(tile[tx][ty + j * 8]);
}

// ---------------------------------------------------------------------------
// h[b,s,:] = x[b,s]*in_w + in_b + pos_encoding(s,:)
// ---------------------------------------------------------------------------
__global__ __launch_bounds__(128) void input_pe_kernel(
    const float* __restrict__ x, const float* __restrict__ in_w,
    const float* __restrict__ in_b, float* __restrict__ h)
{
  const int row = blockIdx.x;          // 0..2047
  const int s = row & (S_ - 1);
  const int c = threadIdx.x * 4;
  const float xv = x[row];
  const float4 wv = *(const float4*)(in_w + c);
  const float4 bv = *(const float4*)(in_b + c);
  const float* wp = (const float*)&wv;
  const float* bp = (const float*)&bv;
  float o[4];
#pragma unroll
  for (int j = 0; j < 4; j++) {
    const int cc = c + j;
    const float di = expf(-(float)(cc & ~1) * (9.210340371976184f / 512.0f));
    const float ang = (float)s * di;
    const float pe = (cc & 1) ? cosf(ang) : sinf(ang);
    o[j] = xv * wp[j] + bp[j] + pe;
  }
  *(float4*)(h + (size_t)row * H_ + c) = make_float4(o[0], o[1], o[2], o[3]);
}

// ---------------------------------------------------------------------------
// LayerNorm: f32 in -> bf16 out (row = 512)
// ---------------------------------------------------------------------------
__global__ __launch_bounds__(128) void ln_kernel(
    const float* __restrict__ hin, const float* __restrict__ g,
    const float* __restrict__ b, unsigned short* __restrict__ nout)
{
  const int row = blockIdx.x;
  const int t = threadIdx.x;
  const int wid = t >> 6, ln_ = t & 63;
  __shared__ float red[2];
  float4 v = ((const float4*)(hin + (size_t)row * H_))[t];
  float sm = v.x + v.y + v.z + v.w;
#pragma unroll
  for (int m = 1; m < 64; m <<= 1) sm += __shfl_xor(sm, m);
  if (ln_ == 0) red[wid] = sm;
  __syncthreads();
  const float mean = (red[0] + red[1]) * (1.0f / 512.0f);
  __syncthreads();
  const float dx = v.x - mean, dy = v.y - mean, dz = v.z - mean, dw = v.w - mean;
  float ss = dx * dx + dy * dy + dz * dz + dw * dw;
#pragma unroll
  for (int m = 1; m < 64; m <<= 1) ss += __shfl_xor(ss, m);
  if (ln_ == 0) red[wid] = ss;
  __syncthreads();
  const float var = (red[0] + red[1]) * (1.0f / 512.0f);
  const float rs = rsqrtf(var + 1e-5f);
  const float4 gv = ((const float4*)g)[t];
  const float4 bv = ((const float4*)b)[t];
  ushort4 o;
  o.x = f2b(dx * rs * gv.x + bv.x);
  o.y = f2b(dy * rs * gv.y + bv.y);
  o.z = f2b(dz * rs * gv.z + bv.z);
  o.w = f2b(dw * rs * gv.w + bv.w);
  ((ushort4*)(nout + (size_t)row * H_))[t] = o;
}

// ---------------------------------------------------------------------------
// GEMM: C[M,N] = epi(A[M,K](bf16) @ Bt[N,K]^T(bf16) + bias[N])
// EPI: 1 = f32 out += (residual in-place), 2 = gelu -> bf16, 3 = f32 out,
//      5 = fused QKV epilogue: col<512 -> q (scaled 0.125, bf16),
//          col<1024 -> k (bf16), else -> v transposed into vt[B][512][S]
// 128x128 tile, BK=32, 4 waves (2x2 of 64x64), mfma_f32_16x16x32_bf16
// ---------------------------------------------------------------------------
template <int EPI>
__global__ __launch_bounds__(256, 2) void gemm_kernel(
    const unsigned short* __restrict__ A, const unsigned short* __restrict__ Bt,
    const float* __restrict__ bias, void* __restrict__ Cout, int M, int N, int K,
    const float* __restrict__ bias2, const float* __restrict__ bias3,
    void* __restrict__ C2, void* __restrict__ C3)
{
  constexpr int LDK = 56;   // padded LDS stride
  __shared__ unsigned short Alds[128 * LDK];
  __shared__ unsigned short Blds[128 * LDK];
  const int tid = threadIdx.x;
  const int w = tid >> 6, lane = tid & 63, lr = lane & 15, lg = lane >> 4;
  const int m0 = blockIdx.x * 128, n0 = blockIdx.y * 128;
  const int wm = (w >> 1) * 64, wn = (w & 1) * 64;

  const int e0 = tid * 8;
  const int r0 = e0 >> 5, c0 = e0 & 31;
  const unsigned short* Ap0 = A + (size_t)(m0 + r0) * K + c0;
  const unsigned short* Ap1 = Ap0 + (size_t)64 * K;
  const unsigned short* Bp0 = Bt + (size_t)(n0 + r0) * K + c0;
  const unsigned short* Bp1 = Bp0 + (size_t)64 * K;
  unsigned short* AL0 = Alds + r0 * LDK + c0;
  unsigned short* AL1 = AL0 + 64 * LDK;
  unsigned short* BL0 = Blds + r0 * LDK + c0;
  unsigned short* BL1 = BL0 + 64 * LDK;

  const f32x4 zero4 = {0.f, 0.f, 0.f, 0.f};
  f32x4 acc[4][4];
#pragma unroll
  for (int i = 0; i < 4; i++)
#pragma unroll
    for (int j = 0; j < 4; j++) acc[i][j] = zero4;

  for (int kt = 0; kt < K; kt += 32) {
    const int4 a0 = *(const int4*)(Ap0 + kt);
    const int4 a1 = *(const int4*)(Ap1 + kt);
    const int4 b0 = *(const int4*)(Bp0 + kt);
    const int4 b1 = *(const int4*)(Bp1 + kt);
    __syncthreads();
    *(int4*)AL0 = a0; *(int4*)AL1 = a1;
    *(int4*)BL0 = b0; *(int4*)BL1 = b1;
    __syncthreads();
    bf16x8 af[4], bfr[4];
#pragma unroll
    for (int mi = 0; mi < 4; mi++)
      af[mi] = *(const bf16x8*)(Alds + (wm + mi * 16 + lr) * LDK + lg * 8);
#pragma unroll
    for (int ni = 0; ni < 4; ni++)
      bfr[ni] = *(const bf16x8*)(Blds + (wn + ni * 16 + lr) * LDK + lg * 8);
#pragma unroll
    for (int mi = 0; mi < 4; mi++)
#pragma unroll
      for (int ni = 0; ni < 4; ni++)
        acc[mi][ni] = __builtin_amdgcn_mfma_f32_16x16x32_bf16(af[mi], bfr[ni], acc[mi][ni], 0, 0, 0);
  }

#pragma unroll
  for (int mi = 0; mi < 4; mi++) {
#pragma unroll
    for (int ni = 0; ni < 4; ni++) {
      const int col = n0 + wn + ni * 16 + lr;
      if constexpr (EPI == 5) {
        if (col < 512) {
          const float bs = bias[col];
#pragma unroll
          for (int r = 0; r < 4; r++) {
            const int row = m0 + wm + mi * 16 + lg * 4 + r;
            ((unsigned short*)Cout)[(size_t)row * 512 + col] =
                f2b((acc[mi][ni][r] + bs) * 0.125f);
          }
        } else if (col < 1024) {
          const float bs = bias2[col - 512];
#pragma unroll
          for (int r = 0; r < 4; r++) {
            const int row = m0 + wm + mi * 16 + lg * 4 + r;
            ((unsigned short*)C2)[(size_t)row * 512 + (col - 512)] =
                f2b(acc[mi][ni][r] + bs);
          }
        } else {
          const float bs = bias3[col - 1024];
          const int row0_ = m0 + wm + mi * 16 + lg * 4;
          const int bb = row0_ >> 10, ssi = row0_ & 1023;
          ushort4 pk;
          pk.x = f2b(acc[mi][ni][0] + bs);
          pk.y = f2b(acc[mi][ni][1] + bs);
          pk.z = f2b(acc[mi][ni][2] + bs);
          pk.w = f2b(acc[mi][ni][3] + bs);
          *(ushort4*)((unsigned short*)C3 + ((size_t)(bb * 512 + (col - 1024))) * 1024 + ssi) = pk;
        }
      } else {
        const float bs = bias[col];
#pragma unroll
        for (int r = 0; r < 4; r++) {
          const int row = m0 + wm + mi * 16 + lg * 4 + r;
          float val = acc[mi][ni][r] + bs;
          const size_t idx = (size_t)row * N + col;
          if constexpr (EPI == 1) {
            ((float*)Cout)[idx] += val;
          } else if constexpr (EPI == 2) {
            val = 0.5f * val * (1.0f + erff(val * 0.7071067811865475f));
            ((unsigned short*)Cout)[idx] = f2b(val);
          } else {  // 3
            ((float*)Cout)[idx] = val;
          }
        }
      }
    }
  }
}

// ---------------------------------------------------------------------------
// Fused attention: scores (MFMA, K*Q^T swapped) -> LDS -> exact top-k threshold
// via atomic-free bitwise binary search (ballot+popcount) + softmax in-register
// -> probs f32 to d_out + bf16 in LDS -> PV (MFMA, split-K across waves).
// Block: 256 threads, 16 q-rows of one (b,nh). Grid (S/16, B*NH).
// q is pre-scaled by 0.125 in the QKV epilogue. LDS 66 KB -> 2 blocks/CU.
// ---------------------------------------------------------------------------
__global__ __launch_bounds__(256, 2) void attn_fused_kernel(
    const unsigned short* __restrict__ qbf, const unsigned short* __restrict__ kbf,
    const unsigned short* __restrict__ vt, float* __restrict__ attnL,
    unsigned short* __restrict__ obf)
{
  constexpr int LDF = 1032;                 // padded f32 row stride
  __shared__ float sc[16 * LDF];            // 66 KB
  const int mblk = blockIdx.x, bnh = blockIdx.y;
  const int b = bnh >> 3, nh = bnh & 7;
  const int tid = threadIdx.x, w = tid >> 6, lane = tid & 63;
  const int lr = lane & 15, lg = lane >> 4;
  const int row0 = mblk * 16;

  const unsigned short* qbase = qbf + ((size_t)(b * S_ + row0)) * H_ + nh * HD_;
  const unsigned short* kbase = kbf + (size_t)(b * S_) * H_ + nh * HD_;

  const f32x4 zero4 = {0.f, 0.f, 0.f, 0.f};

  // ---- Phase 1: scores. mfma(K-rows, Q-rows): D[col=q(lr), row=k(lg*4+r)] ----
  {
    f32x4 acc[16];
#pragma unroll
    for (int kt = 0; kt < 16; kt++) acc[kt] = zero4;
    bf16x8 qf[2];
    qf[0] = *(const bf16x8*)(qbase + (size_t)lr * H_ + lg * 8);
    qf[1] = *(const bf16x8*)(qbase + (size_t)lr * H_ + 32 + lg * 8);
    const int kw0 = w * 256;
#pragma unroll
    for (int kt = 0; kt < 16; kt++) {
      const unsigned short* kp = kbase + (size_t)(kw0 + kt * 16 + lr) * H_ + lg * 8;
      const bf16x8 kf0 = *(const bf16x8*)(kp);
      const bf16x8 kf1 = *(const bf16x8*)(kp + 32);
      acc[kt] = __builtin_amdgcn_mfma_f32_16x16x32_bf16(kf0, qf[0], acc[kt], 0, 0, 0);
      acc[kt] = __builtin_amdgcn_mfma_f32_16x16x32_bf16(kf1, qf[1], acc[kt], 0, 0, 0);
    }
#pragma unroll
    for (int kt = 0; kt < 16; kt++)
      *(f32x4*)(sc + (size_t)lr * LDF + kw0 + kt * 16 + lg * 4) = acc[kt];
  }
  __syncthreads();

  // ---- Phase 2: per-row exact k-th-largest via bitwise binary search + softmax.
  // Wave w owns rows w*4 .. w*4+3; the full 1024-score row lives in wave regs.
#pragma unroll 1
  for (int rr = 0; rr < 4; rr++) {
    const int row = w * 4 + rr;
    float* rowp = sc + (size_t)row * LDF;
    float v[16];
#pragma unroll
    for (int j = 0; j < 8; j++) {
      const float2 t2 = *(const float2*)(rowp + 2 * lane + j * 128);
      v[2 * j] = t2.x; v[2 * j + 1] = t2.y;
    }
    unsigned int keys[16];
#pragma unroll
    for (int j = 0; j < 16; j++) {
      const unsigned int u = __float_as_uint(v[j]);
      keys[j] = (u & 0x80000000u) ? ~u : (u | 0x80000000u);
    }
    // exact k-th largest key: build bits high->low; all lanes uniform.
    unsigned int prefix = 0u;
#pragma unroll 1
    for (int bit = 31; bit >= 0; bit--) {
      const unsigned int cand = prefix | (1u << bit);
      int cnt = 0;
#pragma unroll
      for (int j = 0; j < 16; j++)
        cnt += (int)__popcll(__ballot(keys[j] >= cand));
      if (cnt >= KTOP_) prefix = cand;
    }
    const unsigned int fb = (prefix & 0x80000000u) ? (prefix & 0x7fffffffu) : ~prefix;
    const float thresh = __uint_as_float(fb);

    float mx = v[0];
#pragma unroll
    for (int j = 1; j < 16; j++) mx = fmaxf(mx, v[j]);
#pragma unroll
    for (int m = 1; m < 64; m <<= 1) mx = fmaxf(mx, __shfl_xor(mx, m));
    float p[16];
    float ssum = 0.f;
#pragma unroll
    for (int j = 0; j < 16; j++) {
      const float e = expf(v[j] - mx);
      p[j] = (v[j] >= thresh) ? e : 0.f;
      ssum += p[j];
    }
#pragma unroll
    for (int m = 1; m < 64; m <<= 1) ssum += __shfl_xor(ssum, m);
    const float inv = 1.0f / ssum;
    float* outrow = attnL + (size_t)bnh * S_ * S_ + (size_t)(row0 + row) * S_;
    unsigned short* prow = (unsigned short*)rowp;
#pragma unroll
    for (int j = 0; j < 8; j++) {
      const float p0 = p[2 * j] * inv, p1 = p[2 * j + 1] * inv;
      *(float2*)(outrow + 2 * lane + j * 128) = make_float2(p0, p1);
      const unsigned int pk = ((unsigned int)f2b(p1) << 16) | (unsigned int)f2b(p0);
      *(unsigned int*)(prow + 2 * lane + j * 128) = pk;
    }
  }
  __syncthreads();

  // ---- Phase 3: PV, split-K across waves (wave w covers k in [w*256,w*256+256)) ----
  const unsigned short* vb = vt + (size_t)(b * 512 + nh * HD_) * S_;
  f32x4 oacc[4];
#pragma unroll
  for (int ni = 0; ni < 4; ni++) oacc[ni] = zero4;
  const unsigned short* scu = (const unsigned short*)sc;
#pragma unroll
  for (int ks = 0; ks < 8; ks++) {
    const int k0 = w * 256 + ks * 32;
    const bf16x8 pf = *(const bf16x8*)(scu + (size_t)lr * (2 * LDF) + k0 + lg * 8);
    bf16x8 vfr[4];
#pragma unroll
    for (int ni = 0; ni < 4; ni++)
      vfr[ni] = *(const bf16x8*)(vb + (size_t)(ni * 16 + lr) * S_ + k0 + lg * 8);
#pragma unroll
    for (int ni = 0; ni < 4; ni++)
      oacc[ni] = __builtin_amdgcn_mfma_f32_16x16x32_bf16(pf, vfr[ni], oacc[ni], 0, 0, 0);
  }
  __syncthreads();   // all waves done reading probs before overwrite
  float* red = sc + w * 1024;   // [16 rows][64 cols] partial per wave
#pragma unroll
  for (int ni = 0; ni < 4; ni++)
#pragma unroll
    for (int r = 0; r < 4; r++)
      red[(lg * 4 + r) * 64 + ni * 16 + lr] = oacc[ni][r];
  __syncthreads();
  {
    const int orow = tid >> 4, oc0 = (tid & 15) * 4;
    const float* rp = sc + orow * 64 + oc0;
    float4 s0 = *(const float4*)rp;
#pragma unroll
    for (int ww = 1; ww < 4; ww++) {
      const float4 a = *(const float4*)(rp + ww * 1024);
      s0.x += a.x; s0.y += a.y; s0.z += a.z; s0.w += a.w;
    }
    ushort4 o1;
    o1.x = f2b(s0.x); o1.y = f2b(s0.y); o1.z = f2b(s0.z); o1.w = f2b(s0.w);
    unsigned short* dst = obf + (size_t)(b * S_ + row0 + orow) * H_ + nh * HD_ + oc0;
    *(ushort4*)dst = o1;
  }
}

// ---------------------------------------------------------------------------
extern "C" void kernel_launch(void* const* d_in, const int* in_sizes, int n_in,
                              void* d_out, int out_size, void* d_ws, size_t ws_size,
                              hipStream_t stream)
{
  (void)in_sizes; (void)n_in; (void)out_size; (void)ws_size;
  const float* x     = (const float*)d_in[0];
  const float* in_w  = (const float*)d_in[1];
  const float* in_b  = (const float*)d_in[2];
  const float* ln1_g = (const float*)d_in[3];
  const float* ln1_b = (const float*)d_in[4];
  const float* qw    = (const float*)d_in[5];
  const float* qbias = (const float*)d_in[6];
  const float* kw    = (const float*)d_in[7];
  const float* kbias = (const float*)d_in[8];
  const float* vw    = (const float*)d_in[9];
  const float* vbias = (const float*)d_in[10];
  const float* ow    = (const float*)d_in[11];
  const float* obias = (const float*)d_in[12];
  const float* ln2_g = (const float*)d_in[13];
  const float* ln2_b = (const float*)d_in[14];
  const float* w1    = (const float*)d_in[15];
  const float* b1    = (const float*)d_in[16];
  const float* w2    = (const float*)d_in[17];
  const float* b2    = (const float*)d_in[18];
  const float* fn_g  = (const float*)d_in[19];
  const float* fn_b  = (const float*)d_in[20];
  const float* out_w = (const float*)d_in[21];
  const float* out_b = (const float*)d_in[22];

  char* ws = (char*)d_ws;
  size_t off = 0;
  auto alloc = [&](size_t bytes) -> void* {
    void* p = ws + off;
    off += (bytes + 255) & ~(size_t)255;
    return p;
  };
  float* h             = (float*)alloc((size_t)BS_ * H_ * 4);
  unsigned short* Wqkvt = (unsigned short*)alloc((size_t)L_ * 1536 * H_ * 2);
  unsigned short* Wot  = (unsigned short*)alloc((size_t)L_ * H_ * H_ * 2);
  unsigned short* W1t  = (unsigned short*)alloc((size_t)L_ * MLP_ * H_ * 2);
  unsigned short* W2t  = (unsigned short*)alloc((size_t)L_ * H_ * MLP_ * 2);
  unsigned short* OWt  = (unsigned short*)alloc((size_t)OUT_ * H_ * 2);
  unsigned short* nbf  = (unsigned short*)alloc((size_t)BS_ * H_ * 2);
  unsigned short* qbf  = (unsigned short*)alloc((size_t)BS_ * H_ * 2);
  unsigned short* kbf  = (unsigned short*)alloc((size_t)BS_ * H_ * 2);
  unsigned short* vtb  = (unsigned short*)alloc((size_t)B_ * 512 * S_ * 2);
  unsigned short* obf  = (unsigned short*)alloc((size_t)BS_ * H_ * 2);
  unsigned short* tbf  = (unsigned short*)alloc((size_t)BS_ * MLP_ * 2);

  float* attn_base = (float*)d_out + (size_t)BS_ * OUT_;

  const dim3 tb(256);
  transpose_qkvo_kernel<<<dim3(16, 16, 16), tb, 0, stream>>>(qw, kw, vw, ow, Wqkvt, Wot);
  transpose_conv_kernel<<<dim3(64, 16, 4), tb, 0, stream>>>(w1, W1t, H_, MLP_);
  transpose_conv_kernel<<<dim3(16, 64, 4), tb, 0, stream>>>(w2, W2t, MLP_, H_);
  transpose_conv_kernel<<<dim3(4, 16, 1),  tb, 0, stream>>>(out_w, OWt, H_, OUT_);

  input_pe_kernel<<<dim3(BS_), dim3(128), 0, stream>>>(x, in_w, in_b, h);

  for (int l = 0; l < L_; l++) {
    float* attnL = attn_base + (size_t)l * 16 * S_ * S_;
    ln_kernel<<<dim3(BS_), dim3(128), 0, stream>>>(h, ln1_g + l * H_, ln1_b + l * H_, nbf);
    gemm_kernel<5><<<dim3(16, 12), tb, 0, stream>>>(
        nbf, Wqkvt + (size_t)l * 1536 * H_, qbias + l * H_, qbf, BS_, 1536, H_,
        kbias + l * H_, vbias + l * H_, kbf, vtb);
    attn_fused_kernel<<<dim3(64, 16), tb, 0, stream>>>(qbf, kbf, vtb, attnL, obf);
    gemm_kernel<1><<<dim3(16, 4), tb, 0, stream>>>(
        obf, Wot + (size_t)l * H_ * H_, obias + l * H_, h, BS_, H_, H_,
        nullptr, nullptr, nullptr, nullptr);
    ln_kernel<<<dim3(BS_), dim3(128), 0, stream>>>(h, ln2_g + l * H_, ln2_b + l * H_, nbf);
    gemm_kernel<2><<<dim3(16, 16), tb, 0, stream>>>(
        nbf, W1t + (size_t)l * MLP_ * H_, b1 + l * MLP_, tbf, BS_, MLP_, H_,
        nullptr, nullptr, nullptr, nullptr);
    gemm_kernel<1><<<dim3(16, 4), tb, 0, stream>>>(
        tbf, W2t + (size_t)l * H_ * MLP_, b2 + l * H_, h, BS_, H_, MLP_,
        nullptr, nullptr, nullptr, nullptr);
  }

  ln_kernel<<<dim3(BS_), dim3(128), 0, stream>>>(h, fn_g, fn_b, nbf);
  gemm_kernel<3><<<dim3(16, 1), tb, 0, stream>>>(
      nbf, OWt, out_b, d_out, BS_, OUT_, H_,
      nullptr, nullptr, nullptr, nullptr);
}

// Round 5
// 1037.346 us; speedup vs baseline: 1.3003x; 1.1510x over previous
//
#include <hip/hip_runtime.h>
#include <math.h>

#define DEVINL __device__ __forceinline__

constexpr int S_   = 1024;
constexpr int H_   = 512;
constexpr int NH_  = 8;
constexpr int L_   = 4;
constexpr int HD_  = 64;
constexpr int MLP_ = 2048;
constexpr int OUT_ = 128;
constexpr int B_   = 2;
constexpr int BS_  = 2048;   // B*S
constexpr int KTOP_ = 204;

typedef __bf16 bf16x8 __attribute__((ext_vector_type(8)));
typedef float f32x4 __attribute__((ext_vector_type(4)));

DEVINL unsigned short f2b(float f) {
  unsigned int u = __float_as_uint(f);
  unsigned int r = (u + 0x7fffu + ((u >> 16) & 1u)) >> 16;  // RNE
  return (unsigned short)r;
}

// async global -> LDS, 16 B per lane; lds dst must be wave-uniform base,
// HW writes base + lane*16. Global src is per-lane.
DEVINL void gload16(const unsigned short* g, unsigned short* l) {
  __builtin_amdgcn_global_load_lds(
      (const __attribute__((address_space(1))) unsigned int*)g,
      (__attribute__((address_space(3))) unsigned int*)l,
      16, 0, 0);
}

// ---------------------------------------------------------------------------
// Generic transpose + f32->bf16 convert: src f32 [z][R][C] -> dst bf16 [z][C][R]
// ---------------------------------------------------------------------------
__global__ __launch_bounds__(256) void transpose_conv_kernel(
    const float* __restrict__ src, unsigned short* __restrict__ dst, int R, int C)
{
  __shared__ float tile[32][33];
  const size_t base = (size_t)blockIdx.z * R * C;
  src += base; dst += base;
  const int c0 = blockIdx.x * 32;
  const int r0 = blockIdx.y * 32;
  const int tx = threadIdx.x & 31;
  const int ty = threadIdx.x >> 5;   // 0..7
#pragma unroll
  for (int j = 0; j < 4; j++)
    tile[ty + j * 8][tx] = src[(size_t)(r0 + ty + j * 8) * C + c0 + tx];
  __syncthreads();
#pragma unroll
  for (int j = 0; j < 4; j++)
    dst[(size_t)(c0 + ty + j * 8) * R + r0 + tx] = f2b(tile[tx][ty + j * 8]);
}

// ---------------------------------------------------------------------------
// Batched transpose of the four [L][512][512] weights.
// q/k/v go into Wqkvt [L][1536][512] (row blocks 0/512/1024), o -> Wot.
// grid (16,16,16): z = which*4 + layer
// ---------------------------------------------------------------------------
__global__ __launch_bounds__(256) void transpose_qkvo_kernel(
    const float* __restrict__ qw, const float* __restrict__ kw,
    const float* __restrict__ vw, const float* __restrict__ ow,
    unsigned short* __restrict__ qkv, unsigned short* __restrict__ ot)
{
  __shared__ float tile[32][33];
  const int z = blockIdx.z;
  const int which = z >> 2, l = z & 3;
  const float* src = (which == 0 ? qw : which == 1 ? kw : which == 2 ? vw : ow)
                     + (size_t)l * 512 * 512;
  unsigned short* dst = (which < 3)
      ? (qkv + (size_t)l * 1536 * 512 + (size_t)which * 512 * 512)
      : (ot + (size_t)l * 512 * 512);
  const int c0 = blockIdx.x * 32;
  const int r0 = blockIdx.y * 32;
  const int tx = threadIdx.x & 31;
  const int ty = threadIdx.x >> 5;
#pragma unroll
  for (int j = 0; j < 4; j++)
    tile[ty + j * 8][tx] = src[(size_t)(r0 + ty + j * 8) * 512 + c0 + tx];
  __syncthreads();
#pragma unroll
  for (int j = 0; j < 4; j++)
    dst[(size_t)(c0 + ty + j * 8) * 512 + r0 + tx] = f2b(tile[tx][ty + j * 8]);
}

// ---------------------------------------------------------------------------
// h[b,s,:] = x[b,s]*in_w + in_b + pos_encoding(s,:)
// ---------------------------------------------------------------------------
__global__ __launch_bounds__(128) void input_pe_kernel(
    const float* __restrict__ x, const float* __restrict__ in_w,
    const float* __restrict__ in_b, float* __restrict__ h)
{
  const int row = blockIdx.x;          // 0..2047
  const int s = row & (S_ - 1);
  const int c = threadIdx.x * 4;
  const float xv = x[row];
  const float4 wv = *(const float4*)(in_w + c);
  const float4 bv = *(const float4*)(in_b + c);
  const float* wp = (const float*)&wv;
  const float* bp = (const float*)&bv;
  float o[4];
#pragma unroll
  for (int j = 0; j < 4; j++) {
    const int cc = c + j;
    const float di = expf(-(float)(cc & ~1) * (9.210340371976184f / 512.0f));
    const float ang = (float)s * di;
    const float pe = (cc & 1) ? cosf(ang) : sinf(ang);
    o[j] = xv * wp[j] + bp[j] + pe;
  }
  *(float4*)(h + (size_t)row * H_ + c) = make_float4(o[0], o[1], o[2], o[3]);
}

// ---------------------------------------------------------------------------
// LayerNorm: f32 in -> bf16 out (row = 512)
// ---------------------------------------------------------------------------
__global__ __launch_bounds__(128) void ln_kernel(
    const float* __restrict__ hin, const float* __restrict__ g,
    const float* __restrict__ b, unsigned short* __restrict__ nout)
{
  const int row = blockIdx.x;
  const int t = threadIdx.x;
  const int wid = t >> 6, ln_ = t & 63;
  __shared__ float red[2];
  float4 v = ((const float4*)(hin + (size_t)row * H_))[t];
  float sm = v.x + v.y + v.z + v.w;
#pragma unroll
  for (int m = 1; m < 64; m <<= 1) sm += __shfl_xor(sm, m);
  if (ln_ == 0) red[wid] = sm;
  __syncthreads();
  const float mean = (red[0] + red[1]) * (1.0f / 512.0f);
  __syncthreads();
  const float dx = v.x - mean, dy = v.y - mean, dz = v.z - mean, dw = v.w - mean;
  float ss = dx * dx + dy * dy + dz * dz + dw * dw;
#pragma unroll
  for (int m = 1; m < 64; m <<= 1) ss += __shfl_xor(ss, m);
  if (ln_ == 0) red[wid] = ss;
  __syncthreads();
  const float var = (red[0] + red[1]) * (1.0f / 512.0f);
  const float rs = rsqrtf(var + 1e-5f);
  const float4 gv = ((const float4*)g)[t];
  const float4 bv = ((const float4*)b)[t];
  ushort4 o;
  o.x = f2b(dx * rs * gv.x + bv.x);
  o.y = f2b(dy * rs * gv.y + bv.y);
  o.z = f2b(dz * rs * gv.z + bv.z);
  o.w = f2b(dw * rs * gv.w + bv.w);
  ((ushort4*)(nout + (size_t)row * H_))[t] = o;
}

// ---------------------------------------------------------------------------
// GEMM (m97 structure): C[M,N] = epi(A[M,Kstride](bf16) @ Bt[N,Kstride]^T + bias)
// Staging via global_load_lds width=16, linear LDS [128][32], BK=32,
// 4 waves (2x2 of 64x64), mfma_f32_16x16x32_bf16, 2 barriers per K-step.
// blockIdx.z = K-split chunk (A/Bt advanced by z*Klen; bias applied by z==0).
// EPI: 2 = gelu -> bf16, 3 = f32 out, 5 = fused QKV epilogue,
//      6 = f32 atomicAdd (residual accumulate, split-K safe)
// ---------------------------------------------------------------------------
template <int EPI>
__global__ __launch_bounds__(256, 2) void gemm_kernel(
    const unsigned short* __restrict__ A, const unsigned short* __restrict__ Bt,
    const float* __restrict__ bias, void* __restrict__ Cout,
    int M, int N, int Klen, int Kstride,
    const float* __restrict__ bias2, const float* __restrict__ bias3,
    void* __restrict__ C2, void* __restrict__ C3)
{
  __shared__ unsigned short Alds[128 * 32];
  __shared__ unsigned short Blds[128 * 32];
  const int tid = threadIdx.x;
  const int w = tid >> 6, lane = tid & 63, lr = lane & 15, lg = lane >> 4;
  const int m0 = blockIdx.x * 128, n0 = blockIdx.y * 128;
  const int wm = (w >> 1) * 64, wn = (w & 1) * 64;

  A  += (size_t)blockIdx.z * Klen;
  Bt += (size_t)blockIdx.z * Klen;

  // wave w stages A rows [w*32, w*32+32) and B rows [w*32, w*32+32).
  // call c in {0,1}: lane l -> row w*32+c*16+(l>>2), elem col (l&3)*8
  const int srow = w * 32 + (lane >> 2);
  const int scol = (lane & 3) * 8;
  const unsigned short* Ag0 = A + (size_t)(m0 + srow) * Kstride + scol;
  const unsigned short* Ag1 = A + (size_t)(m0 + srow + 16) * Kstride + scol;
  const unsigned short* Bg0 = Bt + (size_t)(n0 + srow) * Kstride + scol;
  const unsigned short* Bg1 = Bt + (size_t)(n0 + srow + 16) * Kstride + scol;
  unsigned short* Al0 = Alds + (w * 32) * 32;        // wave-uniform LDS bases
  unsigned short* Al1 = Alds + (w * 32 + 16) * 32;
  unsigned short* Bl0 = Blds + (w * 32) * 32;
  unsigned short* Bl1 = Blds + (w * 32 + 16) * 32;

  const f32x4 zero4 = {0.f, 0.f, 0.f, 0.f};
  f32x4 acc[4][4];
#pragma unroll
  for (int i = 0; i < 4; i++)
#pragma unroll
    for (int j = 0; j < 4; j++) acc[i][j] = zero4;

  for (int kt = 0; kt < Klen; kt += 32) {
    __syncthreads();                 // previous iteration's ds_reads done
    gload16(Ag0 + kt, Al0);
    gload16(Ag1 + kt, Al1);
    gload16(Bg0 + kt, Bl0);
    gload16(Bg1 + kt, Bl1);
    __syncthreads();                 // compiler drains vmcnt before barrier
    bf16x8 af[4], bfr[4];
#pragma unroll
    for (int mi = 0; mi < 4; mi++)
      af[mi] = *(const bf16x8*)(Alds + (wm + mi * 16 + lr) * 32 + lg * 8);
#pragma unroll
    for (int ni = 0; ni < 4; ni++)
      bfr[ni] = *(const bf16x8*)(Blds + (wn + ni * 16 + lr) * 32 + lg * 8);
#pragma unroll
    for (int mi = 0; mi < 4; mi++)
#pragma unroll
      for (int ni = 0; ni < 4; ni++)
        acc[mi][ni] = __builtin_amdgcn_mfma_f32_16x16x32_bf16(af[mi], bfr[ni], acc[mi][ni], 0, 0, 0);
  }

#pragma unroll
  for (int mi = 0; mi < 4; mi++) {
#pragma unroll
    for (int ni = 0; ni < 4; ni++) {
      const int col = n0 + wn + ni * 16 + lr;
      if constexpr (EPI == 5) {
        if (col < 512) {
          const float bs = bias[col];
#pragma unroll
          for (int r = 0; r < 4; r++) {
            const int row = m0 + wm + mi * 16 + lg * 4 + r;
            ((unsigned short*)Cout)[(size_t)row * 512 + col] =
                f2b((acc[mi][ni][r] + bs) * 0.125f);
          }
        } else if (col < 1024) {
          const float bs = bias2[col - 512];
#pragma unroll
          for (int r = 0; r < 4; r++) {
            const int row = m0 + wm + mi * 16 + lg * 4 + r;
            ((unsigned short*)C2)[(size_t)row * 512 + (col - 512)] =
                f2b(acc[mi][ni][r] + bs);
          }
        } else {
          const float bs = bias3[col - 1024];
          const int row0_ = m0 + wm + mi * 16 + lg * 4;
          const int bb = row0_ >> 10, ssi = row0_ & 1023;
          ushort4 pk;
          pk.x = f2b(acc[mi][ni][0] + bs);
          pk.y = f2b(acc[mi][ni][1] + bs);
          pk.z = f2b(acc[mi][ni][2] + bs);
          pk.w = f2b(acc[mi][ni][3] + bs);
          *(ushort4*)((unsigned short*)C3 + ((size_t)(bb * 512 + (col - 1024))) * 1024 + ssi) = pk;
        }
      } else if constexpr (EPI == 6) {
        const float bs = (blockIdx.z == 0) ? bias[col] : 0.f;
#pragma unroll
        for (int r = 0; r < 4; r++) {
          const int row = m0 + wm + mi * 16 + lg * 4 + r;
          atomicAdd(&((float*)Cout)[(size_t)row * N + col], acc[mi][ni][r] + bs);
        }
      } else {
        const float bs = bias[col];
#pragma unroll
        for (int r = 0; r < 4; r++) {
          const int row = m0 + wm + mi * 16 + lg * 4 + r;
          float val = acc[mi][ni][r] + bs;
          const size_t idx = (size_t)row * N + col;
          if constexpr (EPI == 2) {
            val = 0.5f * val * (1.0f + erff(val * 0.7071067811865475f));
            ((unsigned short*)Cout)[idx] = f2b(val);
          } else {  // 3
            ((float*)Cout)[idx] = val;
          }
        }
      }
    }
  }
}

// ---------------------------------------------------------------------------
// Fused attention: scores (MFMA, K*Q^T swapped) -> LDS -> exact top-k threshold
// via atomic-free bitwise binary search (ballot+popcount) + softmax in-register
// -> probs f32 to d_out + bf16 in LDS -> PV (MFMA, split-K across waves).
// Block: 256 threads, 16 q-rows of one (b,nh). Grid (S/16, B*NH).
// q is pre-scaled by 0.125 in the QKV epilogue. LDS 66 KB -> 2 blocks/CU.
// ---------------------------------------------------------------------------
__global__ __launch_bounds__(256, 2) void attn_fused_kernel(
    const unsigned short* __restrict__ qbf, const unsigned short* __restrict__ kbf,
    const unsigned short* __restrict__ vt, float* __restrict__ attnL,
    unsigned short* __restrict__ obf)
{
  constexpr int LDF = 1032;                 // padded f32 row stride
  __shared__ float sc[16 * LDF];            // 66 KB
  const int mblk = blockIdx.x, bnh = blockIdx.y;
  const int b = bnh >> 3, nh = bnh & 7;
  const int tid = threadIdx.x, w = tid >> 6, lane = tid & 63;
  const int lr = lane & 15, lg = lane >> 4;
  const int row0 = mblk * 16;

  const unsigned short* qbase = qbf + ((size_t)(b * S_ + row0)) * H_ + nh * HD_;
  const unsigned short* kbase = kbf + (size_t)(b * S_) * H_ + nh * HD_;

  const f32x4 zero4 = {0.f, 0.f, 0.f, 0.f};

  // ---- Phase 1: scores. mfma(K-rows, Q-rows): D[col=q(lr), row=k(lg*4+r)] ----
  {
    f32x4 acc[16];
#pragma unroll
    for (int kt = 0; kt < 16; kt++) acc[kt] = zero4;
    bf16x8 qf[2];
    qf[0] = *(const bf16x8*)(qbase + (size_t)lr * H_ + lg * 8);
    qf[1] = *(const bf16x8*)(qbase + (size_t)lr * H_ + 32 + lg * 8);
    const int kw0 = w * 256;
#pragma unroll
    for (int kt = 0; kt < 16; kt++) {
      const unsigned short* kp = kbase + (size_t)(kw0 + kt * 16 + lr) * H_ + lg * 8;
      const bf16x8 kf0 = *(const bf16x8*)(kp);
      const bf16x8 kf1 = *(const bf16x8*)(kp + 32);
      acc[kt] = __builtin_amdgcn_mfma_f32_16x16x32_bf16(kf0, qf[0], acc[kt], 0, 0, 0);
      acc[kt] = __builtin_amdgcn_mfma_f32_16x16x32_bf16(kf1, qf[1], acc[kt], 0, 0, 0);
    }
#pragma unroll
    for (int kt = 0; kt < 16; kt++)
      *(f32x4*)(sc + (size_t)lr * LDF + kw0 + kt * 16 + lg * 4) = acc[kt];
  }
  __syncthreads();

  // ---- Phase 2: per-row exact k-th-largest via bitwise binary search + softmax.
  // Wave w owns rows w*4 .. w*4+3; the full 1024-score row lives in wave regs.
#pragma unroll 1
  for (int rr = 0; rr < 4; rr++) {
    const int row = w * 4 + rr;
    float* rowp = sc + (size_t)row * LDF;
    float v[16];
#pragma unroll
    for (int j = 0; j < 8; j++) {
      const float2 t2 = *(const float2*)(rowp + 2 * lane + j * 128);
      v[2 * j] = t2.x; v[2 * j + 1] = t2.y;
    }
    unsigned int keys[16];
#pragma unroll
    for (int j = 0; j < 16; j++) {
      const unsigned int u = __float_as_uint(v[j]);
      keys[j] = (u & 0x80000000u) ? ~u : (u | 0x80000000u);
    }
    // exact k-th largest key: build bits high->low; all lanes uniform.
    unsigned int prefix = 0u;
#pragma unroll 1
    for (int bit = 31; bit >= 0; bit--) {
      const unsigned int cand = prefix | (1u << bit);
      int cnt = 0;
#pragma unroll
      for (int j = 0; j < 16; j++)
        cnt += (int)__popcll(__ballot(keys[j] >= cand));
      if (cnt >= KTOP_) prefix = cand;
    }
    const unsigned int fb = (prefix & 0x80000000u) ? (prefix & 0x7fffffffu) : ~prefix;
    const float thresh = __uint_as_float(fb);

    float mx = v[0];
#pragma unroll
    for (int j = 1; j < 16; j++) mx = fmaxf(mx, v[j]);
#pragma unroll
    for (int m = 1; m < 64; m <<= 1) mx = fmaxf(mx, __shfl_xor(mx, m));
    float p[16];
    float ssum = 0.f;
#pragma unroll
    for (int j = 0; j < 16; j++) {
      const float e = expf(v[j] - mx);
      p[j] = (v[j] >= thresh) ? e : 0.f;
      ssum += p[j];
    }
#pragma unroll
    for (int m = 1; m < 64; m <<= 1) ssum += __shfl_xor(ssum, m);
    const float inv = 1.0f / ssum;
    float* outrow = attnL + (size_t)bnh * S_ * S_ + (size_t)(row0 + row) * S_;
    unsigned short* prow = (unsigned short*)rowp;
#pragma unroll
    for (int j = 0; j < 8; j++) {
      const float p0 = p[2 * j] * inv, p1 = p[2 * j + 1] * inv;
      *(float2*)(outrow + 2 * lane + j * 128) = make_float2(p0, p1);
      const unsigned int pk = ((unsigned int)f2b(p1) << 16) | (unsigned int)f2b(p0);
      *(unsigned int*)(prow + 2 * lane + j * 128) = pk;
    }
  }
  __syncthreads();

  // ---- Phase 3: PV, split-K across waves (wave w covers k in [w*256,w*256+256)) ----
  const unsigned short* vb = vt + (size_t)(b * 512 + nh * HD_) * S_;
  f32x4 oacc[4];
#pragma unroll
  for (int ni = 0; ni < 4; ni++) oacc[ni] = zero4;
  const unsigned short* scu = (const unsigned short*)sc;
#pragma unroll
  for (int ks = 0; ks < 8; ks++) {
    const int k0 = w * 256 + ks * 32;
    const bf16x8 pf = *(const bf16x8*)(scu + (size_t)lr * (2 * LDF) + k0 + lg * 8);
    bf16x8 vfr[4];
#pragma unroll
    for (int ni = 0; ni < 4; ni++)
      vfr[ni] = *(const bf16x8*)(vb + (size_t)(ni * 16 + lr) * S_ + k0 + lg * 8);
#pragma unroll
    for (int ni = 0; ni < 4; ni++)
      oacc[ni] = __builtin_amdgcn_mfma_f32_16x16x32_bf16(pf, vfr[ni], oacc[ni], 0, 0, 0);
  }
  __syncthreads();   // all waves done reading probs before overwrite
  float* red = sc + w * 1024;   // [16 rows][64 cols] partial per wave
#pragma unroll
  for (int ni = 0; ni < 4; ni++)
#pragma unroll
    for (int r = 0; r < 4; r++)
      red[(lg * 4 + r) * 64 + ni * 16 + lr] = oacc[ni][r];
  __syncthreads();
  {
    const int orow = tid >> 4, oc0 = (tid & 15) * 4;
    const float* rp = sc + orow * 64 + oc0;
    float4 s0 = *(const float4*)rp;
#pragma unroll
    for (int ww = 1; ww < 4; ww++) {
      const float4 a = *(const float4*)(rp + ww * 1024);
      s0.x += a.x; s0.y += a.y; s0.z += a.z; s0.w += a.w;
    }
    ushort4 o1;
    o1.x = f2b(s0.x); o1.y = f2b(s0.y); o1.z = f2b(s0.z); o1.w = f2b(s0.w);
    unsigned short* dst = obf + (size_t)(b * S_ + row0 + orow) * H_ + nh * HD_ + oc0;
    *(ushort4*)dst = o1;
  }
}

// ---------------------------------------------------------------------------
extern "C" void kernel_launch(void* const* d_in, const int* in_sizes, int n_in,
                              void* d_out, int out_size, void* d_ws, size_t ws_size,
                              hipStream_t stream)
{
  (void)in_sizes; (void)n_in; (void)out_size; (void)ws_size;
  const float* x     = (const float*)d_in[0];
  const float* in_w  = (const float*)d_in[1];
  const float* in_b  = (const float*)d_in[2];
  const float* ln1_g = (const float*)d_in[3];
  const float* ln1_b = (const float*)d_in[4];
  const float* qw    = (const float*)d_in[5];
  const float* qbias = (const float*)d_in[6];
  const float* kw    = (const float*)d_in[7];
  const float* kbias = (const float*)d_in[8];
  const float* vw    = (const float*)d_in[9];
  const float* vbias = (const float*)d_in[10];
  const float* ow    = (const float*)d_in[11];
  const float* obias = (const float*)d_in[12];
  const float* ln2_g = (const float*)d_in[13];
  const float* ln2_b = (const float*)d_in[14];
  const float* w1    = (const float*)d_in[15];
  const float* b1    = (const float*)d_in[16];
  const float* w2    = (const float*)d_in[17];
  const float* b2    = (const float*)d_in[18];
  const float* fn_g  = (const float*)d_in[19];
  const float* fn_b  = (const float*)d_in[20];
  const float* out_w = (const float*)d_in[21];
  const float* out_b = (const float*)d_in[22];

  char* ws = (char*)d_ws;
  size_t off = 0;
  auto alloc = [&](size_t bytes) -> void* {
    void* p = ws + off;
    off += (bytes + 255) & ~(size_t)255;
    return p;
  };
  float* h             = (float*)alloc((size_t)BS_ * H_ * 4);
  unsigned short* Wqkvt = (unsigned short*)alloc((size_t)L_ * 1536 * H_ * 2);
  unsigned short* Wot  = (unsigned short*)alloc((size_t)L_ * H_ * H_ * 2);
  unsigned short* W1t  = (unsigned short*)alloc((size_t)L_ * MLP_ * H_ * 2);
  unsigned short* W2t  = (unsigned short*)alloc((size_t)L_ * H_ * MLP_ * 2);
  unsigned short* OWt  = (unsigned short*)alloc((size_t)OUT_ * H_ * 2);
  unsigned short* nbf  = (unsigned short*)alloc((size_t)BS_ * H_ * 2);
  unsigned short* qbf  = (unsigned short*)alloc((size_t)BS_ * H_ * 2);
  unsigned short* kbf  = (unsigned short*)alloc((size_t)BS_ * H_ * 2);
  unsigned short* vtb  = (unsigned short*)alloc((size_t)B_ * 512 * S_ * 2);
  unsigned short* obf  = (unsigned short*)alloc((size_t)BS_ * H_ * 2);
  unsigned short* tbf  = (unsigned short*)alloc((size_t)BS_ * MLP_ * 2);

  float* attn_base = (float*)d_out + (size_t)BS_ * OUT_;

  const dim3 tb(256);
  transpose_qkvo_kernel<<<dim3(16, 16, 16), tb, 0, stream>>>(qw, kw, vw, ow, Wqkvt, Wot);
  transpose_conv_kernel<<<dim3(64, 16, 4), tb, 0, stream>>>(w1, W1t, H_, MLP_);
  transpose_conv_kernel<<<dim3(16, 64, 4), tb, 0, stream>>>(w2, W2t, MLP_, H_);
  transpose_conv_kernel<<<dim3(4, 16, 1),  tb, 0, stream>>>(out_w, OWt, H_, OUT_);

  input_pe_kernel<<<dim3(BS_), dim3(128), 0, stream>>>(x, in_w, in_b, h);

  for (int l = 0; l < L_; l++) {
    float* attnL = attn_base + (size_t)l * 16 * S_ * S_;
    ln_kernel<<<dim3(BS_), dim3(128), 0, stream>>>(h, ln1_g + l * H_, ln1_b + l * H_, nbf);
    gemm_kernel<5><<<dim3(16, 12), tb, 0, stream>>>(
        nbf, Wqkvt + (size_t)l * 1536 * H_, qbias + l * H_, qbf, BS_, 1536, H_, H_,
        kbias + l * H_, vbias + l * H_, kbf, vtb);
    attn_fused_kernel<<<dim3(64, 16), tb, 0, stream>>>(qbf, kbf, vtb, attnL, obf);
    gemm_kernel<6><<<dim3(16, 4, 2), tb, 0, stream>>>(
        obf, Wot + (size_t)l * H_ * H_, obias + l * H_, h, BS_, H_, 256, H_,
        nullptr, nullptr, nullptr, nullptr);
    ln_kernel<<<dim3(BS_), dim3(128), 0, stream>>>(h, ln2_g + l * H_, ln2_b + l * H_, nbf);
    gemm_kernel<2><<<dim3(16, 16), tb, 0, stream>>>(
        nbf, W1t + (size_t)l * MLP_ * H_, b1 + l * MLP_, tbf, BS_, MLP_, H_, H_,
        nullptr, nullptr, nullptr, nullptr);
    gemm_kernel<6><<<dim3(16, 4, 4), tb, 0, stream>>>(
        tbf, W2t + (size_t)l * H_ * MLP_, b2 + l * H_, h, BS_, H_, 512, MLP_,
        nullptr, nullptr, nullptr, nullptr);
  }

  ln_kernel<<<dim3(BS_), dim3(128), 0, stream>>>(h, fn_g, fn_b, nbf);
  gemm_kernel<3><<<dim3(16, 1), tb, 0, stream>>>(
      nbf, OWt, out_b, d_out, BS_, OUT_, H_, H_,
      nullptr, nullptr, nullptr, nullptr);
}

// Round 7
// 1035.066 us; speedup vs baseline: 1.3032x; 1.0022x over previous
//
#include <hip/hip_runtime.h>
#include <math.h>

#define DEVINL __device__ __forceinline__

constexpr int S_   = 1024;
constexpr int H_   = 512;
constexpr int NH_  = 8;
constexpr int L_   = 4;
constexpr int HD_  = 64;
constexpr int MLP_ = 2048;
constexpr int OUT_ = 128;
constexpr int B_   = 2;
constexpr int BS_  = 2048;   // B*S
constexpr int KTOP_ = 204;

typedef __bf16 bf16x8 __attribute__((ext_vector_type(8)));
typedef float f32x4 __attribute__((ext_vector_type(4)));

DEVINL unsigned short f2b(float f) {
  unsigned int u = __float_as_uint(f);
  unsigned int r = (u + 0x7fffu + ((u >> 16) & 1u)) >> 16;  // RNE
  return (unsigned short)r;
}

// async global -> LDS, 16 B per lane; lds dst must be wave-uniform base,
// HW writes base + lane*16. Global src is per-lane.
DEVINL void gload16(const unsigned short* g, unsigned short* l) {
  __builtin_amdgcn_global_load_lds(
      (const __attribute__((address_space(1))) unsigned int*)g,
      (__attribute__((address_space(3))) unsigned int*)l,
      16, 0, 0);
}

// ---------------------------------------------------------------------------
// Unified prep kernel: all weight transposes (f32 [z][R][C] -> bf16 [z][C][R])
// + input projection + positional encoding. Flat grid of 13376 blocks:
//   [0,4096):     qkvo transposes (which*4+layer, 16x16 tiles)
//   [4096,8192):  w1  (R=512,C=2048, 4 layers)
//   [8192,12288): w2  (R=2048,C=512, 4 layers)
//   [12288,12352): out_w (R=512,C=128)
//   [12352,13376): input_pe (2 rows per block)
// ---------------------------------------------------------------------------
__global__ __launch_bounds__(256) void prep_kernel(
    const float* __restrict__ qw, const float* __restrict__ kw,
    const float* __restrict__ vw, const float* __restrict__ ow,
    const float* __restrict__ w1, const float* __restrict__ w2,
    const float* __restrict__ outw,
    const float* __restrict__ x, const float* __restrict__ in_w,
    const float* __restrict__ in_b,
    unsigned short* __restrict__ Wqkvt, unsigned short* __restrict__ Wot,
    unsigned short* __restrict__ W1t, unsigned short* __restrict__ W2t,
    unsigned short* __restrict__ OWt, float* __restrict__ h)
{
  const int bid = blockIdx.x;
  if (bid >= 12352) {
    // ---- input_pe ----
    const int idx = bid - 12352;
    const int row = idx * 2 + (threadIdx.x >> 7);
    const int s = row & (S_ - 1);
    const int c = (threadIdx.x & 127) * 4;
    const float xv = x[row];
    const float4 wv = *(const float4*)(in_w + c);
    const float4 bv = *(const float4*)(in_b + c);
    const float* wp = (const float*)&wv;
    const float* bp = (const float*)&bv;
    float o[4];
#pragma unroll
    for (int j = 0; j < 4; j++) {
      const int cc = c + j;
      const float di = expf(-(float)(cc & ~1) * (9.210340371976184f / 512.0f));
      const float ang = (float)s * di;
      const float pe = (cc & 1) ? cosf(ang) : sinf(ang);
      o[j] = xv * wp[j] + bp[j] + pe;
    }
    *(float4*)(h + (size_t)row * H_ + c) = make_float4(o[0], o[1], o[2], o[3]);
    return;
  }
  // ---- transposes ----
  const float* src; unsigned short* dst; int R, C, cx, ry;
  if (bid < 4096) {
    const int z = bid >> 8, rem = bid & 255;
    const int which = z >> 2, l = z & 3;
    src = (which == 0 ? qw : which == 1 ? kw : which == 2 ? vw : ow)
          + (size_t)l * 512 * 512;
    dst = (which < 3)
        ? (Wqkvt + (size_t)l * 1536 * 512 + (size_t)which * 512 * 512)
        : (Wot + (size_t)l * 512 * 512);
    R = 512; C = 512; cx = rem & 15; ry = rem >> 4;
  } else if (bid < 8192) {
    const int idx = bid - 4096, z = idx >> 10, rem = idx & 1023;
    src = w1 + (size_t)z * 512 * 2048;
    dst = W1t + (size_t)z * 2048 * 512;
    R = 512; C = 2048; cx = rem & 63; ry = rem >> 6;
  } else if (bid < 12288) {
    const int idx = bid - 8192, z = idx >> 10, rem = idx & 1023;
    src = w2 + (size_t)z * 2048 * 512;
    dst = W2t + (size_t)z * 512 * 2048;
    R = 2048; C = 512; cx = rem & 15; ry = rem >> 4;
  } else {
    const int idx = bid - 12288;
    src = outw; dst = OWt;
    R = 512; C = 128; cx = idx & 3; ry = idx >> 2;
  }
  __shared__ float tile[32][33];
  const int c0 = cx * 32, r0 = ry * 32;
  const int tx = threadIdx.x & 31, ty = threadIdx.x >> 5;
#pragma unroll
  for (int j = 0; j < 4; j++)
    tile[ty + j * 8][tx] = src[(size_t)(r0 + ty + j * 8) * C + c0 + tx];
  __syncthreads();
#pragma unroll
  for (int j = 0; j < 4; j++)
    dst[(size_t)(c0 + ty + j * 8) * R + r0 + tx] = f2b(tile[tx][ty + j * 8]);
}

// ---------------------------------------------------------------------------
// LayerNorm: f32 in -> bf16 out (row = 512)
// ---------------------------------------------------------------------------
__global__ __launch_bounds__(128) void ln_kernel(
    const float* __restrict__ hin, const float* __restrict__ g,
    const float* __restrict__ b, unsigned short* __restrict__ nout)
{
  const int row = blockIdx.x;
  const int t = threadIdx.x;
  const int wid = t >> 6, ln_ = t & 63;
  __shared__ float red[2];
  float4 v = ((const float4*)(hin + (size_t)row * H_))[t];
  float sm = v.x + v.y + v.z + v.w;
#pragma unroll
  for (int m = 1; m < 64; m <<= 1) sm += __shfl_xor(sm, m);
  if (ln_ == 0) red[wid] = sm;
  __syncthreads();
  const float mean = (red[0] + red[1]) * (1.0f / 512.0f);
  __syncthreads();
  const float dx = v.x - mean, dy = v.y - mean, dz = v.z - mean, dw = v.w - mean;
  float ss = dx * dx + dy * dy + dz * dz + dw * dw;
#pragma unroll
  for (int m = 1; m < 64; m <<= 1) ss += __shfl_xor(ss, m);
  if (ln_ == 0) red[wid] = ss;
  __syncthreads();
  const float var = (red[0] + red[1]) * (1.0f / 512.0f);
  const float rs = rsqrtf(var + 1e-5f);
  const float4 gv = ((const float4*)g)[t];
  const float4 bv = ((const float4*)b)[t];
  ushort4 o;
  o.x = f2b(dx * rs * gv.x + bv.x);
  o.y = f2b(dy * rs * gv.y + bv.y);
  o.z = f2b(dz * rs * gv.z + bv.z);
  o.w = f2b(dw * rs * gv.w + bv.w);
  ((ushort4*)(nout + (size_t)row * H_))[t] = o;
}

// ---------------------------------------------------------------------------
// GEMM, 2-phase double-buffered (T3-minimum): per K-step, issue next-tile
// global_load_lds into buf^1 BEFORE computing on buf; single __syncthreads()
// per step (implicit vmcnt(0) drain lands after compute overlapped the loads).
// C[M,N] = epi(A[M,Kstride](bf16) @ Bt[N,Kstride]^T + bias).
// 128x128 tile, BK=32, 4 waves (2x2 of 64x64), mfma_f32_16x16x32_bf16.
// blockIdx.z = K-split chunk (A/Bt advanced by z*Klen; bias applied by z==0).
// EPI: 2 = gelu -> bf16, 3 = f32 out, 5 = fused QKV epilogue,
//      6 = f32 atomicAdd (residual accumulate, split-K safe)
// ---------------------------------------------------------------------------
template <int EPI>
__global__ __launch_bounds__(256, 2) void gemm_kernel(
    const unsigned short* __restrict__ A, const unsigned short* __restrict__ Bt,
    const float* __restrict__ bias, void* __restrict__ Cout,
    int M, int N, int Klen, int Kstride,
    const float* __restrict__ bias2, const float* __restrict__ bias3,
    void* __restrict__ C2, void* __restrict__ C3)
{
  __shared__ unsigned short Alds[2][128 * 32];
  __shared__ unsigned short Blds[2][128 * 32];
  const int tid = threadIdx.x;
  const int w = tid >> 6, lane = tid & 63, lr = lane & 15, lg = lane >> 4;
  const int m0 = blockIdx.x * 128, n0 = blockIdx.y * 128;
  const int wm = (w >> 1) * 64, wn = (w & 1) * 64;

  A  += (size_t)blockIdx.z * Klen;
  Bt += (size_t)blockIdx.z * Klen;

  // wave w stages A rows [w*32, w*32+32) and B rows [w*32, w*32+32)
  const int srow = w * 32 + (lane >> 2);
  const int scol = (lane & 3) * 8;
  const unsigned short* Ag0 = A + (size_t)(m0 + srow) * Kstride + scol;
  const unsigned short* Ag1 = A + (size_t)(m0 + srow + 16) * Kstride + scol;
  const unsigned short* Bg0 = Bt + (size_t)(n0 + srow) * Kstride + scol;
  const unsigned short* Bg1 = Bt + (size_t)(n0 + srow + 16) * Kstride + scol;
  const int l0 = (w * 32) * 32;        // wave-uniform LDS element offsets
  const int l1 = (w * 32 + 16) * 32;

  auto STAGE = [&](int buf, int kt) {
    gload16(Ag0 + kt, &Alds[buf][l0]);
    gload16(Ag1 + kt, &Alds[buf][l1]);
    gload16(Bg0 + kt, &Blds[buf][l0]);
    gload16(Bg1 + kt, &Blds[buf][l1]);
  };

  const f32x4 zero4 = {0.f, 0.f, 0.f, 0.f};
  f32x4 acc[4][4];
#pragma unroll
  for (int i = 0; i < 4; i++)
#pragma unroll
    for (int j = 0; j < 4; j++) acc[i][j] = zero4;

  const int nsteps = Klen >> 5;
  STAGE(0, 0);
  __syncthreads();
  int cur = 0;
  for (int t = 0; t < nsteps; t++) {
    if (t + 1 < nsteps) STAGE(cur ^ 1, (t + 1) * 32);
    bf16x8 af[4], bfr[4];
#pragma unroll
    for (int mi = 0; mi < 4; mi++)
      af[mi] = *(const bf16x8*)(&Alds[cur][(wm + mi * 16 + lr) * 32 + lg * 8]);
#pragma unroll
    for (int ni = 0; ni < 4; ni++)
      bfr[ni] = *(const bf16x8*)(&Blds[cur][(wn + ni * 16 + lr) * 32 + lg * 8]);
#pragma unroll
    for (int mi = 0; mi < 4; mi++)
#pragma unroll
      for (int ni = 0; ni < 4; ni++)
        acc[mi][ni] = __builtin_amdgcn_mfma_f32_16x16x32_bf16(af[mi], bfr[ni], acc[mi][ni], 0, 0, 0);
    __syncthreads();   // drains vmcnt(0): next buffer ready; all reads of cur done
    cur ^= 1;
  }

#pragma unroll
  for (int mi = 0; mi < 4; mi++) {
#pragma unroll
    for (int ni = 0; ni < 4; ni++) {
      const int col = n0 + wn + ni * 16 + lr;
      if constexpr (EPI == 5) {
        if (col < 512) {
          const float bs = bias[col];
#pragma unroll
          for (int r = 0; r < 4; r++) {
            const int row = m0 + wm + mi * 16 + lg * 4 + r;
            ((unsigned short*)Cout)[(size_t)row * 512 + col] =
                f2b((acc[mi][ni][r] + bs) * 0.125f);
          }
        } else if (col < 1024) {
          const float bs = bias2[col - 512];
#pragma unroll
          for (int r = 0; r < 4; r++) {
            const int row = m0 + wm + mi * 16 + lg * 4 + r;
            ((unsigned short*)C2)[(size_t)row * 512 + (col - 512)] =
                f2b(acc[mi][ni][r] + bs);
          }
        } else {
          const float bs = bias3[col - 1024];
          const int row0_ = m0 + wm + mi * 16 + lg * 4;
          const int bb = row0_ >> 10, ssi = row0_ & 1023;
          ushort4 pk;
          pk.x = f2b(acc[mi][ni][0] + bs);
          pk.y = f2b(acc[mi][ni][1] + bs);
          pk.z = f2b(acc[mi][ni][2] + bs);
          pk.w = f2b(acc[mi][ni][3] + bs);
          *(ushort4*)((unsigned short*)C3 + ((size_t)(bb * 512 + (col - 1024))) * 1024 + ssi) = pk;
        }
      } else if constexpr (EPI == 6) {
        const float bs = (blockIdx.z == 0) ? bias[col] : 0.f;
#pragma unroll
        for (int r = 0; r < 4; r++) {
          const int row = m0 + wm + mi * 16 + lg * 4 + r;
          atomicAdd(&((float*)Cout)[(size_t)row * N + col], acc[mi][ni][r] + bs);
        }
      } else {
        const float bs = bias[col];
#pragma unroll
        for (int r = 0; r < 4; r++) {
          const int row = m0 + wm + mi * 16 + lg * 4 + r;
          float val = acc[mi][ni][r] + bs;
          const size_t idx = (size_t)row * N + col;
          if constexpr (EPI == 2) {
            val = 0.5f * val * (1.0f + erff(val * 0.7071067811865475f));
            ((unsigned short*)Cout)[idx] = f2b(val);
          } else {  // 3
            ((float*)Cout)[idx] = val;
          }
        }
      }
    }
  }
}

// ---------------------------------------------------------------------------
// Fused attention: scores (MFMA, K*Q^T swapped) -> LDS -> exact top-k threshold
// via atomic-free bitwise binary search (ballot+popcount) + softmax in-register
// -> probs f32 to d_out + bf16 in LDS -> PV (MFMA, split-K across waves).
// Block: 256 threads, 16 q-rows of one (b,nh). Grid (S/16, B*NH).
// q is pre-scaled by 0.125 in the QKV epilogue. LDS 66 KB -> 2 blocks/CU.
// ---------------------------------------------------------------------------
__global__ __launch_bounds__(256, 2) void attn_fused_kernel(
    const unsigned short* __restrict__ qbf, const unsigned short* __restrict__ kbf,
    const unsigned short* __restrict__ vt, float* __restrict__ attnL,
    unsigned short* __restrict__ obf)
{
  constexpr int LDF = 1032;                 // padded f32 row stride
  __shared__ float sc[16 * LDF];            // 66 KB
  const int mblk = blockIdx.x, bnh = blockIdx.y;
  const int b = bnh >> 3, nh = bnh & 7;
  const int tid = threadIdx.x, w = tid >> 6, lane = tid & 63;
  const int lr = lane & 15, lg = lane >> 4;
  const int row0 = mblk * 16;

  const unsigned short* qbase = qbf + ((size_t)(b * S_ + row0)) * H_ + nh * HD_;
  const unsigned short* kbase = kbf + (size_t)(b * S_) * H_ + nh * HD_;

  const f32x4 zero4 = {0.f, 0.f, 0.f, 0.f};

  // ---- Phase 1: scores. mfma(K-rows, Q-rows): D[col=q(lr), row=k(lg*4+r)] ----
  {
    f32x4 acc[16];
#pragma unroll
    for (int kt = 0; kt < 16; kt++) acc[kt] = zero4;
    bf16x8 qf[2];
    qf[0] = *(const bf16x8*)(qbase + (size_t)lr * H_ + lg * 8);
    qf[1] = *(const bf16x8*)(qbase + (size_t)lr * H_ + 32 + lg * 8);
    const int kw0 = w * 256;
#pragma unroll
    for (int kt = 0; kt < 16; kt++) {
      const unsigned short* kp = kbase + (size_t)(kw0 + kt * 16 + lr) * H_ + lg * 8;
      const bf16x8 kf0 = *(const bf16x8*)(kp);
      const bf16x8 kf1 = *(const bf16x8*)(kp + 32);
      acc[kt] = __builtin_amdgcn_mfma_f32_16x16x32_bf16(kf0, qf[0], acc[kt], 0, 0, 0);
      acc[kt] = __builtin_amdgcn_mfma_f32_16x16x32_bf16(kf1, qf[1], acc[kt], 0, 0, 0);
    }
#pragma unroll
    for (int kt = 0; kt < 16; kt++)
      *(f32x4*)(sc + (size_t)lr * LDF + kw0 + kt * 16 + lg * 4) = acc[kt];
  }
  __syncthreads();

  // ---- Phase 2: per-row exact k-th-largest via bitwise binary search + softmax.
#pragma unroll 1
  for (int rr = 0; rr < 4; rr++) {
    const int row = w * 4 + rr;
    float* rowp = sc + (size_t)row * LDF;
    float v[16];
#pragma unroll
    for (int j = 0; j < 8; j++) {
      const float2 t2 = *(const float2*)(rowp + 2 * lane + j * 128);
      v[2 * j] = t2.x; v[2 * j + 1] = t2.y;
    }
    unsigned int keys[16];
#pragma unroll
    for (int j = 0; j < 16; j++) {
      const unsigned int u = __float_as_uint(v[j]);
      keys[j] = (u & 0x80000000u) ? ~u : (u | 0x80000000u);
    }
    unsigned int prefix = 0u;
#pragma unroll 1
    for (int bit = 31; bit >= 0; bit--) {
      const unsigned int cand = prefix | (1u << bit);
      int cnt = 0;
#pragma unroll
      for (int j = 0; j < 16; j++)
        cnt += (int)__popcll(__ballot(keys[j] >= cand));
      if (cnt >= KTOP_) prefix = cand;
    }
    const unsigned int fb = (prefix & 0x80000000u) ? (prefix & 0x7fffffffu) : ~prefix;
    const float thresh = __uint_as_float(fb);

    float mx = v[0];
#pragma unroll
    for (int j = 1; j < 16; j++) mx = fmaxf(mx, v[j]);
#pragma unroll
    for (int m = 1; m < 64; m <<= 1) mx = fmaxf(mx, __shfl_xor(mx, m));
    float p[16];
    float ssum = 0.f;
#pragma unroll
    for (int j = 0; j < 16; j++) {
      const float e = expf(v[j] - mx);
      p[j] = (v[j] >= thresh) ? e : 0.f;
      ssum += p[j];
    }
#pragma unroll
    for (int m = 1; m < 64; m <<= 1) ssum += __shfl_xor(ssum, m);
    const float inv = 1.0f / ssum;
    float* outrow = attnL + (size_t)bnh * S_ * S_ + (size_t)(row0 + row) * S_;
    unsigned short* prow = (unsigned short*)rowp;
#pragma unroll
    for (int j = 0; j < 8; j++) {
      const float p0 = p[2 * j] * inv, p1 = p[2 * j + 1] * inv;
      *(float2*)(outrow + 2 * lane + j * 128) = make_float2(p0, p1);
      const unsigned int pk = ((unsigned int)f2b(p1) << 16) | (unsigned int)f2b(p0);
      *(unsigned int*)(prow + 2 * lane + j * 128) = pk;
    }
  }
  __syncthreads();

  // ---- Phase 3: PV, split-K across waves ----
  const unsigned short* vb = vt + (size_t)(b * 512 + nh * HD_) * S_;
  f32x4 oacc[4];
#pragma unroll
  for (int ni = 0; ni < 4; ni++) oacc[ni] = zero4;
  const unsigned short* scu = (const unsigned short*)sc;
#pragma unroll
  for (int ks = 0; ks < 8; ks++) {
    const int k0 = w * 256 + ks * 32;
    const bf16x8 pf = *(const bf16x8*)(scu + (size_t)lr * (2 * LDF) + k0 + lg * 8);
    bf16x8 vfr[4];
#pragma unroll
    for (int ni = 0; ni < 4; ni++)
      vfr[ni] = *(const bf16x8*)(vb + (size_t)(ni * 16 + lr) * S_ + k0 + lg * 8);
#pragma unroll
    for (int ni = 0; ni < 4; ni++)
      oacc[ni] = __builtin_amdgcn_mfma_f32_16x16x32_bf16(pf, vfr[ni], oacc[ni], 0, 0, 0);
  }
  __syncthreads();
  float* red = sc + w * 1024;
#pragma unroll
  for (int ni = 0; ni < 4; ni++)
#pragma unroll
    for (int r = 0; r < 4; r++)
      red[(lg * 4 + r) * 64 + ni * 16 + lr] = oacc[ni][r];
  __syncthreads();
  {
    const int orow = tid >> 4, oc0 = (tid & 15) * 4;
    const float* rp = sc + orow * 64 + oc0;
    float4 s0 = *(const float4*)rp;
#pragma unroll
    for (int ww = 1; ww < 4; ww++) {
      const float4 a = *(const float4*)(rp + ww * 1024);
      s0.x += a.x; s0.y += a.y; s0.z += a.z; s0.w += a.w;
    }
    ushort4 o1;
    o1.x = f2b(s0.x); o1.y = f2b(s0.y); o1.z = f2b(s0.z); o1.w = f2b(s0.w);
    unsigned short* dst = obf + (size_t)(b * S_ + row0 + orow) * H_ + nh * HD_ + oc0;
    *(ushort4*)dst = o1;
  }
}

// ---------------------------------------------------------------------------
extern "C" void kernel_launch(void* const* d_in, const int* in_sizes, int n_in,
                              void* d_out, int out_size, void* d_ws, size_t ws_size,
                              hipStream_t stream)
{
  (void)in_sizes; (void)n_in; (void)out_size; (void)ws_size;
  const float* x     = (const float*)d_in[0];
  const float* in_w  = (const float*)d_in[1];
  const float* in_b  = (const float*)d_in[2];
  const float* ln1_g = (const float*)d_in[3];
  const float* ln1_b = (const float*)d_in[4];
  const float* qw    = (const float*)d_in[5];
  const float* qbias = (const float*)d_in[6];
  const float* kw    = (const float*)d_in[7];
  const float* kbias = (const float*)d_in[8];
  const float* vw    = (const float*)d_in[9];
  const float* vbias = (const float*)d_in[10];
  const float* ow    = (const float*)d_in[11];
  const float* obias = (const float*)d_in[12];
  const float* ln2_g = (const float*)d_in[13];
  const float* ln2_b = (const float*)d_in[14];
  const float* w1    = (const float*)d_in[15];
  const float* b1    = (const float*)d_in[16];
  const float* w2    = (const float*)d_in[17];
  const float* b2    = (const float*)d_in[18];
  const float* fn_g  = (const float*)d_in[19];
  const float* fn_b  = (const float*)d_in[20];
  const float* out_w = (const float*)d_in[21];
  const float* out_b = (const float*)d_in[22];

  char* ws = (char*)d_ws;
  size_t off = 0;
  auto alloc = [&](size_t bytes) -> void* {
    void* p = ws + off;
    off += (bytes + 255) & ~(size_t)255;
    return p;
  };
  float* h             = (float*)alloc((size_t)BS_ * H_ * 4);
  unsigned short* Wqkvt = (unsigned short*)alloc((size_t)L_ * 1536 * H_ * 2);
  unsigned short* Wot  = (unsigned short*)alloc((size_t)L_ * H_ * H_ * 2);
  unsigned short* W1t  = (unsigned short*)alloc((size_t)L_ * MLP_ * H_ * 2);
  unsigned short* W2t  = (unsigned short*)alloc((size_t)L_ * H_ * MLP_ * 2);
  unsigned short* OWt  = (unsigned short*)alloc((size_t)OUT_ * H_ * 2);
  unsigned short* nbf  = (unsigned short*)alloc((size_t)BS_ * H_ * 2);
  unsigned short* qbf  = (unsigned short*)alloc((size_t)BS_ * H_ * 2);
  unsigned short* kbf  = (unsigned short*)alloc((size_t)BS_ * H_ * 2);
  unsigned short* vtb  = (unsigned short*)alloc((size_t)B_ * 512 * S_ * 2);
  unsigned short* obf  = (unsigned short*)alloc((size_t)BS_ * H_ * 2);
  unsigned short* tbf  = (unsigned short*)alloc((size_t)BS_ * MLP_ * 2);

  float* attn_base = (float*)d_out + (size_t)BS_ * OUT_;

  const dim3 tb(256);
  prep_kernel<<<dim3(13376), tb, 0, stream>>>(
      qw, kw, vw, ow, w1, w2, out_w, x, in_w, in_b,
      Wqkvt, Wot, W1t, W2t, OWt, h);

  for (int l = 0; l < L_; l++) {
    float* attnL = attn_base + (size_t)l * 16 * S_ * S_;
    ln_kernel<<<dim3(BS_), dim3(128), 0, stream>>>(h, ln1_g + l * H_, ln1_b + l * H_, nbf);
    gemm_kernel<5><<<dim3(16, 12), tb, 0, stream>>>(
        nbf, Wqkvt + (size_t)l * 1536 * H_, qbias + l * H_, qbf, BS_, 1536, H_, H_,
        kbias + l * H_, vbias + l * H_, kbf, vtb);
    attn_fused_kernel<<<dim3(64, 16), tb, 0, stream>>>(qbf, kbf, vtb, attnL, obf);
    gemm_kernel<6><<<dim3(16, 4, 2), tb, 0, stream>>>(
        obf, Wot + (size_t)l * H_ * H_, obias + l * H_, h, BS_, H_, 256, H_,
        nullptr, nullptr, nullptr, nullptr);
    ln_kernel<<<dim3(BS_), dim3(128), 0, stream>>>(h, ln2_g + l * H_, ln2_b + l * H_, nbf);
    gemm_kernel<2><<<dim3(16, 16), tb, 0, stream>>>(
        nbf, W1t + (size_t)l * MLP_ * H_, b1 + l * MLP_, tbf, BS_, MLP_, H_, H_,
        nullptr, nullptr, nullptr, nullptr);
    gemm_kernel<6><<<dim3(16, 4, 4), tb, 0, stream>>>(
        tbf, W2t + (size_t)l * H_ * MLP_, b2 + l * H_, h, BS_, H_, 512, MLP_,
        nullptr, nullptr, nullptr, nullptr);
  }

  ln_kernel<<<dim3(BS_), dim3(128), 0, stream>>>(h, fn_g, fn_b, nbf);
  gemm_kernel<3><<<dim3(16, 1), tb, 0, stream>>>(
      nbf, OWt, out_b, d_out, BS_, OUT_, H_, H_,
      nullptr, nullptr, nullptr, nullptr);
}